// Round 4
// baseline (1030.967 us; speedup 1.0000x reference)
//
#include <hip/hip_runtime.h>
#include <cstdint>
#include <cstddef>

#define NN 30000
#define NE 480000
#define HALF 15000

__device__ __forceinline__ float leakyf(float x){ return x > 0.f ? x : 0.2f * x; }
__device__ __forceinline__ float eluf(float x){ return x > 0.f ? x : expm1f(x); }

struct F4 { float x, y, z, w; };

__device__ __forceinline__ F4 ld4(const float* p){
  float4 v = *(const float4*)p;
  return F4{v.x, v.y, v.z, v.w};
}

// ---------------- CSR build ----------------

__global__ void zero_int_kernel(int* __restrict__ p, int n){
  int i = blockIdx.x * blockDim.x + threadIdx.x;
  if (i < n) p[i] = 0;
}

__global__ void count_kernel(const int* __restrict__ dst, int* __restrict__ deg, int E){
  int i = blockIdx.x * blockDim.x + threadIdx.x;
  if (i < E) atomicAdd(&deg[dst[i]], 1);
}

__global__ void scan_kernel(const int* __restrict__ deg, int* __restrict__ offs, int n){
  __shared__ int sh[1024];
  __shared__ int carry;
  int tid = threadIdx.x;
  if (tid == 0){ carry = 0; offs[0] = 0; }
  __syncthreads();
  for (int base = 0; base < n; base += 1024){
    int i = base + tid;
    int v = (i < n) ? deg[i] : 0;
    sh[tid] = v;
    __syncthreads();
    for (int o = 1; o < 1024; o <<= 1){
      int t = (tid >= o) ? sh[tid - o] : 0;
      __syncthreads();
      sh[tid] += t;
      __syncthreads();
    }
    int c = carry;
    int inc = sh[tid];
    int total = sh[1023];
    if (i < n) offs[i + 1] = c + inc;
    __syncthreads();
    if (tid == 0) carry = c + total;
    __syncthreads();
  }
}

__global__ void scatter_kernel(const int* __restrict__ src, const int* __restrict__ dst,
                               const int* __restrict__ et, const int* __restrict__ offs,
                               int* __restrict__ cursor, int* __restrict__ csr_src,
                               int* __restrict__ csr_et, int E){
  int i = blockIdx.x * blockDim.x + threadIdx.x;
  if (i < E){
    int d = dst[i];
    int pos = offs[d] + atomicAdd(&cursor[d], 1);
    csr_src[pos] = src[i];
    csr_et[pos]  = et[i];
  }
}

// ---------------- basis-space aggregation ----------------
// Layer 1: agg1[n, b*32+c] = (1/deg) * sum_{e in(n)} comp[et,b] * x[src, c]
// wave per node; lanes 0-31 = even edges, lanes 32-63 = odd edges; c = lane&31.

__global__ void agg1_kernel(const float* __restrict__ x, const float* __restrict__ comp,
                            const int* __restrict__ offs, const int* __restrict__ csr_src,
                            const int* __restrict__ csr_et, float* __restrict__ agg){
  int wid  = (blockIdx.x * blockDim.x + threadIdx.x) >> 6;
  int lane = threadIdx.x & 63;
  if (wid >= NN) return;
  int c = lane & 31, half = lane >> 5;
  int n0 = offs[wid], n1 = offs[wid + 1];
  float a0 = 0.f, a1 = 0.f, a2 = 0.f, a3 = 0.f;
  for (int k = n0 + half; k < n1; k += 2){
    int s = csr_src[k], e = csr_et[k];
    float v = x[(size_t)s * 32 + c];
    F4 cp = ld4(comp + (size_t)e * 4);
    a0 += cp.x * v; a1 += cp.y * v; a2 += cp.z * v; a3 += cp.w * v;
  }
  a0 += __shfl_xor(a0, 32);
  a1 += __shfl_xor(a1, 32);
  a2 += __shfl_xor(a2, 32);
  a3 += __shfl_xor(a3, 32);
  int dg = n1 - n0;
  float sc = 1.f / (float)(dg > 0 ? dg : 1);
  if (lane < 32){
    float* ar = agg + (size_t)wid * 128 + c;
    ar[0]  = a0 * sc;
    ar[32] = a1 * sc;
    ar[64] = a2 * sc;
    ar[96] = a3 * sc;
  }
}

// Layer 3: agg[nloc, b*256 + lane*4 + j] = (1/deg) * sum_e comp[et,b] * h2[src, lane*4+j]
// wave per node (within a node half); lane covers 4 channels (float4); 2-edge unroll.

__global__ void agg3_kernel(const float* __restrict__ h2, const float* __restrict__ comp,
                            const int* __restrict__ offs, const int* __restrict__ csr_src,
                            const int* __restrict__ csr_et, float* __restrict__ agg,
                            int node_base, int count){
  int wid  = (blockIdx.x * blockDim.x + threadIdx.x) >> 6;
  int lane = threadIdx.x & 63;
  if (wid >= count) return;
  int node = node_base + wid;
  int n0 = offs[node], n1 = offs[node + 1];
  F4 acc[4];
  #pragma unroll
  for (int b = 0; b < 4; b++) acc[b] = F4{0.f, 0.f, 0.f, 0.f};
  int k = n0;
  for (; k + 1 < n1; k += 2){
    int s0 = csr_src[k],     e0 = csr_et[k];
    int s1 = csr_src[k + 1], e1 = csr_et[k + 1];
    F4 v0 = ld4(h2 + (size_t)s0 * 256 + lane * 4);
    F4 v1 = ld4(h2 + (size_t)s1 * 256 + lane * 4);
    F4 c0 = ld4(comp + (size_t)e0 * 4);
    F4 c1 = ld4(comp + (size_t)e1 * 4);
    acc[0].x += c0.x*v0.x + c1.x*v1.x; acc[0].y += c0.x*v0.y + c1.x*v1.y;
    acc[0].z += c0.x*v0.z + c1.x*v1.z; acc[0].w += c0.x*v0.w + c1.x*v1.w;
    acc[1].x += c0.y*v0.x + c1.y*v1.x; acc[1].y += c0.y*v0.y + c1.y*v1.y;
    acc[1].z += c0.y*v0.z + c1.y*v1.z; acc[1].w += c0.y*v0.w + c1.y*v1.w;
    acc[2].x += c0.z*v0.x + c1.z*v1.x; acc[2].y += c0.z*v0.y + c1.z*v1.y;
    acc[2].z += c0.z*v0.z + c1.z*v1.z; acc[2].w += c0.z*v0.w + c1.z*v1.w;
    acc[3].x += c0.w*v0.x + c1.w*v1.x; acc[3].y += c0.w*v0.y + c1.w*v1.y;
    acc[3].z += c0.w*v0.z + c1.w*v1.z; acc[3].w += c0.w*v0.w + c1.w*v1.w;
  }
  if (k < n1){
    int s = csr_src[k], e = csr_et[k];
    F4 v = ld4(h2 + (size_t)s * 256 + lane * 4);
    F4 cp = ld4(comp + (size_t)e * 4);
    acc[0].x += cp.x*v.x; acc[0].y += cp.x*v.y; acc[0].z += cp.x*v.z; acc[0].w += cp.x*v.w;
    acc[1].x += cp.y*v.x; acc[1].y += cp.y*v.y; acc[1].z += cp.y*v.z; acc[1].w += cp.y*v.w;
    acc[2].x += cp.z*v.x; acc[2].y += cp.z*v.y; acc[2].z += cp.z*v.z; acc[2].w += cp.z*v.w;
    acc[3].x += cp.w*v.x; acc[3].y += cp.w*v.y; acc[3].z += cp.w*v.z; acc[3].w += cp.w*v.w;
  }
  int dg = n1 - n0;
  float sc = 1.f / (float)(dg > 0 ? dg : 1);
  float* ar = agg + (size_t)wid * 1024 + lane * 4;
  #pragma unroll
  for (int b = 0; b < 4; b++)
    *(float4*)(ar + b * 256) = make_float4(acc[b].x * sc, acc[b].y * sc, acc[b].z * sc, acc[b].w * sc);
}

// ---------------- chunked partial GEMM: Y[c][row,0:64] = X[row, chunk c] @ W[c] ----
// thread = row, blockIdx.y = chunk c. W row-major [FIN,64] per chunk (wstride 64).

template<int FIN>
__global__ __launch_bounds__(256) void gemm_chunk_kernel(
    const float* __restrict__ X, int xstride, int xchunk,
    const float* __restrict__ Wb, int wchunk,
    float* __restrict__ Y, int nrows)
{
  int row = blockIdx.x * 256 + threadIdx.x;
  int cg = blockIdx.y;
  if (row >= nrows) return;
  const float* W  = Wb + (size_t)cg * wchunk;
  const float* xr = X + (size_t)row * xstride + (size_t)cg * xchunk;
  float acc[64];
  #pragma unroll
  for (int c = 0; c < 64; c++) acc[c] = 0.f;
  for (int k0 = 0; k0 < FIN; k0 += 16){
    float xv[16];
    #pragma unroll
    for (int j = 0; j < 4; j++){
      float4 v = *(const float4*)(xr + k0 + j * 4);
      xv[j*4] = v.x; xv[j*4+1] = v.y; xv[j*4+2] = v.z; xv[j*4+3] = v.w;
    }
    #pragma unroll 4
    for (int kk = 0; kk < 16; kk++){
      const float* Wr = W + (size_t)(k0 + kk) * 64;
      float xk = xv[kk];
      #pragma unroll
      for (int c = 0; c < 64; c += 4){
        float4 bv = *(const float4*)(Wr + c);
        acc[c]   += xk * bv.x;
        acc[c+1] += xk * bv.y;
        acc[c+2] += xk * bv.z;
        acc[c+3] += xk * bv.w;
      }
    }
  }
  float* yr = Y + (size_t)cg * nrows * 64 + (size_t)row * 64;
  #pragma unroll
  for (int c = 0; c < 64; c += 4)
    *(float4*)(yr + c) = make_float4(acc[c], acc[c+1], acc[c+2], acc[c+3]);
}

// reduce partials + bias + elu
template<int NC>
__global__ void reduce_kernel(const float* __restrict__ parts, const float* __restrict__ bias,
                              float* __restrict__ out, int nrows){
  int idx = blockIdx.x * blockDim.x + threadIdx.x;
  if (idx >= nrows * 64) return;
  size_t stride = (size_t)nrows * 64;
  float s = 0.f;
  #pragma unroll
  for (int j = 0; j < NC; j++) s += parts[j * stride + idx];
  out[idx] = eluf(s + bias[idx & 63]);
}

// ---------------- GAT ----------------

// hW = h @ W (64 -> 256), fused attention logits. thread = node, blockIdx.y = head.
template<int FIN, bool ATT>
__global__ __launch_bounds__(256) void gemm_cols64_kernel(
    const float* __restrict__ X, const float* __restrict__ Wb,
    int wstride, int wblock, int ostride,
    const float* __restrict__ atts, const float* __restrict__ attd,
    float* __restrict__ Y, float* __restrict__ as_, float* __restrict__ ad_)
{
  int node = blockIdx.x * 256 + threadIdx.x;
  int cg = blockIdx.y;
  if (node >= NN) return;
  const float* W  = Wb + (size_t)cg * wblock;
  const float* xr = X + (size_t)node * FIN;
  float acc[64];
  #pragma unroll
  for (int c = 0; c < 64; c++) acc[c] = 0.f;
  for (int k0 = 0; k0 < FIN; k0 += 16){
    float xv[16];
    #pragma unroll
    for (int j = 0; j < 4; j++){
      float4 v = *(const float4*)(xr + k0 + j * 4);
      xv[j*4] = v.x; xv[j*4+1] = v.y; xv[j*4+2] = v.z; xv[j*4+3] = v.w;
    }
    #pragma unroll 4
    for (int kk = 0; kk < 16; kk++){
      const float* Wr = W + (size_t)(k0 + kk) * wstride;
      float xk = xv[kk];
      #pragma unroll
      for (int c = 0; c < 64; c += 4){
        float4 bv = *(const float4*)(Wr + c);
        acc[c]   += xk * bv.x;
        acc[c+1] += xk * bv.y;
        acc[c+2] += xk * bv.z;
        acc[c+3] += xk * bv.w;
      }
    }
  }
  float* yr = Y + (size_t)node * ostride + cg * 64;
  #pragma unroll
  for (int c = 0; c < 64; c += 4)
    *(float4*)(yr + c) = make_float4(acc[c], acc[c+1], acc[c+2], acc[c+3]);
  if (ATT){
    float ps = 0.f, pd = 0.f;
    const float* pa = atts + cg * 64;
    const float* pb = attd + cg * 64;
    #pragma unroll
    for (int c = 0; c < 64; c++){ ps += acc[c] * pa[c]; pd += acc[c] * pb[c]; }
    as_[node * 4 + cg] = ps;
    ad_[node * 4 + cg] = pd;
  }
}

// GAT1 softmax-aggregate. one wave per (node, head): lane = channel within head.
__global__ void gat1_agg_kernel(const float* __restrict__ hw, const float* __restrict__ as_,
                                const float* __restrict__ ad_, const float* __restrict__ bias,
                                const int* __restrict__ offs, const int* __restrict__ csr_src,
                                float* __restrict__ out){
  int wid  = (blockIdx.x * blockDim.x + threadIdx.x) >> 6;
  int lane = threadIdx.x & 63;
  if (wid >= NN * 4) return;
  int node = wid >> 2, h = wid & 3;
  int n0 = offs[node], n1 = offs[node + 1];
  float adn = ad_[node * 4 + h];
  float es  = leakyf(as_[node * 4 + h] + adn);
  float m = es;
  for (int k = n0 + lane; k < n1; k += 64){
    int s = csr_src[k];
    m = fmaxf(m, leakyf(as_[s * 4 + h] + adn));
  }
  #pragma unroll
  for (int o = 32; o; o >>= 1) m = fmaxf(m, __shfl_xor(m, o));
  float ps = expf(es - m);
  float den = ps;
  float a = 0.f;
  int k = n0;
  for (; k + 1 < n1; k += 2){
    int s0 = csr_src[k], s1 = csr_src[k + 1];
    float p0 = expf(leakyf(as_[s0 * 4 + h] + adn) - m);
    float p1 = expf(leakyf(as_[s1 * 4 + h] + adn) - m);
    float v0 = hw[(size_t)s0 * 256 + h * 64 + lane];
    float v1 = hw[(size_t)s1 * 256 + h * 64 + lane];
    den += p0 + p1;
    a += p0 * v0 + p1 * v1;
  }
  for (; k < n1; k++){
    int s = csr_src[k];
    float p = expf(leakyf(as_[s * 4 + h] + adn) - m);
    den += p;
    a += p * hw[(size_t)s * 256 + h * 64 + lane];
  }
  a += ps * hw[(size_t)node * 256 + h * 64 + lane];
  out[(size_t)node * 256 + h * 64 + lane] = eluf(a / den + bias[h * 64 + lane]);
}

// hW2 = h3 @ Wg2 (64 -> 12), fused logits. one wave per node, lanes 0..11 active for GEMV.
__global__ void gat_lin2_kernel(const float* __restrict__ h, const float* __restrict__ W,
                                const float* __restrict__ atts, const float* __restrict__ attd,
                                float* __restrict__ hw, float* __restrict__ as_, float* __restrict__ ad_){
  int wid  = (blockIdx.x * blockDim.x + threadIdx.x) >> 6;
  int lane = threadIdx.x & 63;
  if (wid >= NN) return;
  float acc = 0.f;
  if (lane < 12){
    const float* hr = h + (size_t)wid * 64;
    const float* Wc = W + lane;
    #pragma unroll 8
    for (int i = 0; i < 64; i++) acc += hr[i] * Wc[(size_t)i * 12];
    hw[(size_t)wid * 12 + lane] = acc;
  }
  float ts = (lane < 12) ? acc * atts[lane] : 0.f;
  float td = (lane < 12) ? acc * attd[lane] : 0.f;
  int b = (lane < 4) ? lane * 3 : 0;
  float s0 = __shfl(ts, b) + __shfl(ts, b + 1) + __shfl(ts, b + 2);
  float d0 = __shfl(td, b) + __shfl(td, b + 1) + __shfl(td, b + 2);
  if (lane < 4){ as_[wid * 4 + lane] = s0; ad_[wid * 4 + lane] = d0; }
}

// GAT2 (mean over heads) + mean over classes + tanh. one wave per node, lanes over edges.
__global__ void gat2_final_kernel(const float* __restrict__ hw, const float* __restrict__ as_,
                                  const float* __restrict__ ad_, const float* __restrict__ bg2,
                                  const int* __restrict__ offs, const int* __restrict__ csr_src,
                                  float* __restrict__ out){
  int wid  = (blockIdx.x * blockDim.x + threadIdx.x) >> 6;
  int lane = threadIdx.x & 63;
  if (wid >= NN) return;
  int n0 = offs[wid], n1 = offs[wid + 1];
  F4 adn = ld4(ad_ + (size_t)wid * 4);
  F4 asn = ld4(as_ + (size_t)wid * 4);
  F4 es{leakyf(asn.x + adn.x), leakyf(asn.y + adn.y), leakyf(asn.z + adn.z), leakyf(asn.w + adn.w)};
  F4 m = es;
  for (int k = n0 + lane; k < n1; k += 64){
    int s = csr_src[k];
    F4 a = ld4(as_ + (size_t)s * 4);
    m.x = fmaxf(m.x, leakyf(a.x + adn.x));
    m.y = fmaxf(m.y, leakyf(a.y + adn.y));
    m.z = fmaxf(m.z, leakyf(a.z + adn.z));
    m.w = fmaxf(m.w, leakyf(a.w + adn.w));
  }
  #pragma unroll
  for (int o = 32; o; o >>= 1){
    m.x = fmaxf(m.x, __shfl_xor(m.x, o));
    m.y = fmaxf(m.y, __shfl_xor(m.y, o));
    m.z = fmaxf(m.z, __shfl_xor(m.z, o));
    m.w = fmaxf(m.w, __shfl_xor(m.w, o));
  }
  F4 ps{expf(es.x - m.x), expf(es.y - m.y), expf(es.z - m.z), expf(es.w - m.w)};
  float acc[12];
  #pragma unroll
  for (int j = 0; j < 12; j++) acc[j] = 0.f;
  F4 denp{0.f, 0.f, 0.f, 0.f};
  for (int k = n0 + lane; k < n1; k += 64){
    int s = csr_src[k];
    F4 a = ld4(as_ + (size_t)s * 4);
    F4 p{expf(leakyf(a.x + adn.x) - m.x), expf(leakyf(a.y + adn.y) - m.y),
         expf(leakyf(a.z + adn.z) - m.z), expf(leakyf(a.w + adn.w) - m.w)};
    denp.x += p.x; denp.y += p.y; denp.z += p.z; denp.w += p.w;
    const float* hb = hw + (size_t)s * 12;
    F4 h0 = ld4(hb), h1 = ld4(hb + 4), h2 = ld4(hb + 8);
    acc[0] += p.x * h0.x; acc[1]  += p.x * h0.y; acc[2]  += p.x * h0.z;
    acc[3] += p.y * h0.w; acc[4]  += p.y * h1.x; acc[5]  += p.y * h1.y;
    acc[6] += p.z * h1.z; acc[7]  += p.z * h1.w; acc[8]  += p.z * h2.x;
    acc[9] += p.w * h2.y; acc[10] += p.w * h2.z; acc[11] += p.w * h2.w;
  }
  #pragma unroll
  for (int o = 32; o; o >>= 1){
    denp.x += __shfl_xor(denp.x, o);
    denp.y += __shfl_xor(denp.y, o);
    denp.z += __shfl_xor(denp.z, o);
    denp.w += __shfl_xor(denp.w, o);
    #pragma unroll
    for (int j = 0; j < 12; j++) acc[j] += __shfl_xor(acc[j], o);
  }
  if (lane == 0){
    const float* hn = hw + (size_t)wid * 12;
    float dn[4]  = {denp.x + ps.x, denp.y + ps.y, denp.z + ps.z, denp.w + ps.w};
    float psv[4] = {ps.x, ps.y, ps.z, ps.w};
    float tot = 0.f;
    #pragma unroll
    for (int h_ = 0; h_ < 4; h_++){
      #pragma unroll
      for (int c = 0; c < 3; c++){
        float num = acc[h_ * 3 + c] + psv[h_] * hn[h_ * 3 + c];
        tot += num / dn[h_];
      }
    }
    tot = tot / 12.f + (bg2[0] + bg2[1] + bg2[2]) / 3.f;
    out[wid] = tanhf(tot);
  }
}

// ---------------- launch ----------------

extern "C" void kernel_launch(void* const* d_in, const int* in_sizes, int n_in,
                              void* d_out, int out_size, void* d_ws, size_t ws_size,
                              hipStream_t stream){
  const float* x      = (const float*)d_in[0];
  const int*   ei     = (const int*)d_in[1];
  const int*   et     = (const int*)d_in[2];
  const float* basis1 = (const float*)d_in[3];
  const float* comp1  = (const float*)d_in[4];
  const float* root1  = (const float*)d_in[5];
  const float* brg1   = (const float*)d_in[6];
  const float* Wg1    = (const float*)d_in[7];
  const float* atts1  = (const float*)d_in[8];
  const float* attd1  = (const float*)d_in[9];
  const float* bg1    = (const float*)d_in[10];
  const float* basis2 = (const float*)d_in[11];
  const float* comp2  = (const float*)d_in[12];
  const float* root2  = (const float*)d_in[13];
  const float* brg2   = (const float*)d_in[14];
  const float* Wg2    = (const float*)d_in[15];
  const float* atts2  = (const float*)d_in[16];
  const float* attd2  = (const float*)d_in[17];
  const float* bg2    = (const float*)d_in[18];
  float* out = (float*)d_out;

  const int* src = ei;
  const int* dst = ei + NE;

  char* ws = (char*)d_ws;
  size_t off = 0;
  auto alloc = [&](size_t bytes) -> void* {
    void* p = ws + off;
    off = (off + bytes + 255) & ~(size_t)255;
    return p;
  };
  // persistent
  int*   deg     = (int*)alloc((size_t)NN * 4);
  int*   cursor  = (int*)alloc((size_t)NN * 4);
  int*   offs    = (int*)alloc((size_t)(NN + 1) * 4);
  int*   csr_src = (int*)alloc((size_t)NE * 4);
  int*   csr_et  = (int*)alloc((size_t)NE * 4);
  float* h1      = (float*)alloc((size_t)NN * 64 * 4);
  float* h2      = (float*)alloc((size_t)NN * 256 * 4);
  float* h3      = (float*)alloc((size_t)NN * 64 * 4);
  float* hw2     = (float*)alloc((size_t)NN * 12 * 4);
  float* as1     = (float*)alloc((size_t)NN * 4 * 4);
  float* ad1     = (float*)alloc((size_t)NN * 4 * 4);
  float* as2     = (float*)alloc((size_t)NN * 4 * 4);
  float* ad2     = (float*)alloc((size_t)NN * 4 * 4);
  // scratch union S: phase L1 {agg1[NN*128], partsL1[2*NN*64]} ->
  //                  phase GAT1 {hW1[NN*256]} ->
  //                  phase L3 {agg3[HALF*1024], partsL3[5*HALF*64]}
  float* S       = (float*)alloc(((size_t)HALF * 1024 + (size_t)5 * HALF * 64) * 4);
  float* agg1    = S;
  float* partsL1 = S + (size_t)NN * 128;
  float* hW1     = S;
  float* agg3    = S;
  float* partsL3 = S + (size_t)HALF * 1024;
  (void)ws_size; (void)n_in; (void)in_sizes; (void)out_size;

  const int BLK = 256;
  int gridN  = (NN + BLK - 1) / BLK;
  int gridE  = (NE + BLK - 1) / BLK;
  int gridW  = (NN + 3) / 4;            // 4 waves/block, 1 node/wave
  int gridW4 = (NN * 4 + 3) / 4;        // 1 (node,head)/wave
  int gridWH = (HALF + 3) / 4;          // 1 node/wave over a half
  int gridR  = (NN + 255) / 256;        // thread-per-node GEMM rows
  int gridRH = (HALF + 255) / 256;

  // CSR build
  zero_int_kernel<<<gridN, BLK, 0, stream>>>(deg, NN);
  zero_int_kernel<<<gridN, BLK, 0, stream>>>(cursor, NN);
  count_kernel<<<gridE, BLK, 0, stream>>>(dst, deg, NE);
  scan_kernel<<<1, 1024, 0, stream>>>(deg, offs, NN);
  scatter_kernel<<<gridE, BLK, 0, stream>>>(src, dst, et, offs, cursor, csr_src, csr_et, NE);

  // Layer 1: RGCN (32 -> 64), basis-space aggregation first
  agg1_kernel<<<gridW, BLK, 0, stream>>>(x, comp1, offs, csr_src, csr_et, agg1);
  gemm_chunk_kernel<128><<<dim3(gridR, 1), BLK, 0, stream>>>(agg1, 128, 0, basis1, 0, partsL1, NN);
  gemm_chunk_kernel<32><<<dim3(gridR, 1), BLK, 0, stream>>>(x, 32, 0, root1, 0, partsL1 + (size_t)NN * 64, NN);
  reduce_kernel<2><<<(NN * 64 + 255) / 256, BLK, 0, stream>>>(partsL1, brg1, h1, NN);

  // Layer 2: GAT (64 -> 256 concat) + elu  (linear fused with attention logits)
  gemm_cols64_kernel<64, true><<<dim3(gridR, 4), BLK, 0, stream>>>(
      h1, Wg1, 256, 64, 256, atts1, attd1, hW1, as1, ad1);
  gat1_agg_kernel<<<gridW4, BLK, 0, stream>>>(hW1, as1, ad1, bg1, offs, csr_src, h2);

  // Layer 3: RGCN (256 -> 64), basis-space aggregation, two node-halves
  for (int half = 0; half < 2; half++){
    int base = half * HALF;
    agg3_kernel<<<gridWH, BLK, 0, stream>>>(h2, comp2, offs, csr_src, csr_et, agg3, base, HALF);
    gemm_chunk_kernel<256><<<dim3(gridRH, 4), BLK, 0, stream>>>(agg3, 1024, 256, basis2, 256 * 64, partsL3, HALF);
    gemm_chunk_kernel<256><<<dim3(gridRH, 1), BLK, 0, stream>>>(h2 + (size_t)base * 256, 256, 0, root2, 0,
                                                                partsL3 + (size_t)4 * HALF * 64, HALF);
    reduce_kernel<5><<<(HALF * 64 + 255) / 256, BLK, 0, stream>>>(partsL3, brg2, h3 + (size_t)base * 64, HALF);
  }

  // Layer 4: GAT (64 -> 4x3, mean heads) + mean classes + tanh
  gat_lin2_kernel<<<gridW, BLK, 0, stream>>>(h3, Wg2, atts2, attd2, hw2, as2, ad2);
  gat2_final_kernel<<<gridW, BLK, 0, stream>>>(hw2, as2, ad2, bg2, offs, csr_src, out);
}

// Round 5
// 572.363 us; speedup vs baseline: 1.8012x; 1.8012x over previous
//
#include <hip/hip_runtime.h>
#include <cstdint>
#include <cstddef>

#define NN 30000
#define NE 480000
#define HALF 15000

__device__ __forceinline__ float leakyf(float x){ return x > 0.f ? x : 0.2f * x; }
__device__ __forceinline__ float eluf(float x){ return x > 0.f ? x : expm1f(x); }

struct F4 { float x, y, z, w; };

__device__ __forceinline__ F4 ld4(const float* p){
  float4 v = *(const float4*)p;
  return F4{v.x, v.y, v.z, v.w};
}

// ---------------- CSR build ----------------

__global__ void zero_int_kernel(int* __restrict__ p, int n){
  int i = blockIdx.x * blockDim.x + threadIdx.x;
  if (i < n) p[i] = 0;
}

__global__ void count_kernel(const int* __restrict__ dst, int* __restrict__ deg, int E){
  int i = blockIdx.x * blockDim.x + threadIdx.x;
  if (i < E) atomicAdd(&deg[dst[i]], 1);
}

// parallel scan: per-block inclusive scan
__global__ void scan1_kernel(const int* __restrict__ deg, int* __restrict__ offs,
                             int* __restrict__ bsum){
  __shared__ int sh[256];
  int blk = blockIdx.x, t = threadIdx.x, i = blk * 256 + t;
  int v = (i < NN) ? deg[i] : 0;
  sh[t] = v; __syncthreads();
  for (int o = 1; o < 256; o <<= 1){
    int tv = (t >= o) ? sh[t - o] : 0;
    __syncthreads();
    sh[t] += tv;
    __syncthreads();
  }
  if (i < NN) offs[i + 1] = sh[t];
  if (t == 255) bsum[blk] = sh[255];
}

__global__ void scan2_kernel(int* __restrict__ bsum, int nb){
  __shared__ int sh[256];
  int t = threadIdx.x;
  int v = (t < nb) ? bsum[t] : 0;
  sh[t] = v; __syncthreads();
  for (int o = 1; o < 256; o <<= 1){
    int tv = (t >= o) ? sh[t - o] : 0;
    __syncthreads();
    sh[t] += tv;
    __syncthreads();
  }
  if (t < nb) bsum[t] = sh[t];  // inclusive block sums
}

__global__ void scan3_kernel(const int* __restrict__ bsum, int* __restrict__ offs){
  int i = blockIdx.x * 256 + threadIdx.x;
  if (i == 0) offs[0] = 0;
  if (i < NN){
    int blk = i >> 8;
    int add = blk ? bsum[blk - 1] : 0;
    offs[i + 1] += add;
  }
}

__global__ void scatter_kernel(const int* __restrict__ src, const int* __restrict__ dst,
                               const int* __restrict__ et, const int* __restrict__ offs,
                               int* __restrict__ cursor, int* __restrict__ csr_src,
                               int* __restrict__ csr_et, int E){
  int i = blockIdx.x * blockDim.x + threadIdx.x;
  if (i < E){
    int d = dst[i];
    int pos = offs[d] + atomicAdd(&cursor[d], 1);
    csr_src[pos] = src[i];
    csr_et[pos]  = et[i];
  }
}

// ---------------- basis-space aggregation ----------------
// Layer 1: agg1[n, b*32+c] = (1/deg) * sum_{e in(n)} comp[et,b] * x[src, c]

__global__ void agg1_kernel(const float* __restrict__ x, const float* __restrict__ comp,
                            const int* __restrict__ offs, const int* __restrict__ csr_src,
                            const int* __restrict__ csr_et, float* __restrict__ agg){
  int wid  = (blockIdx.x * blockDim.x + threadIdx.x) >> 6;
  int lane = threadIdx.x & 63;
  if (wid >= NN) return;
  int c = lane & 31, half = lane >> 5;
  int n0 = offs[wid], n1 = offs[wid + 1];
  float a0 = 0.f, a1 = 0.f, a2 = 0.f, a3 = 0.f;
  for (int k = n0 + half; k < n1; k += 2){
    int s = csr_src[k], e = csr_et[k];
    float v = x[(size_t)s * 32 + c];
    F4 cp = ld4(comp + (size_t)e * 4);
    a0 += cp.x * v; a1 += cp.y * v; a2 += cp.z * v; a3 += cp.w * v;
  }
  a0 += __shfl_xor(a0, 32);
  a1 += __shfl_xor(a1, 32);
  a2 += __shfl_xor(a2, 32);
  a3 += __shfl_xor(a3, 32);
  int dg = n1 - n0;
  float sc = 1.f / (float)(dg > 0 ? dg : 1);
  if (lane < 32){
    float* ar = agg + (size_t)wid * 128 + c;
    ar[0]  = a0 * sc;
    ar[32] = a1 * sc;
    ar[64] = a2 * sc;
    ar[96] = a3 * sc;
  }
}

// Layer 3: agg[nloc, b*256 + c] = (1/deg) * sum_e comp[et,b] * h2[src, c]
__global__ void agg3_kernel(const float* __restrict__ h2, const float* __restrict__ comp,
                            const int* __restrict__ offs, const int* __restrict__ csr_src,
                            const int* __restrict__ csr_et, float* __restrict__ agg,
                            int node_base, int count){
  int wid  = (blockIdx.x * blockDim.x + threadIdx.x) >> 6;
  int lane = threadIdx.x & 63;
  if (wid >= count) return;
  int node = node_base + wid;
  int n0 = offs[node], n1 = offs[node + 1];
  F4 acc[4];
  #pragma unroll
  for (int b = 0; b < 4; b++) acc[b] = F4{0.f, 0.f, 0.f, 0.f};
  int k = n0;
  for (; k + 1 < n1; k += 2){
    int s0 = csr_src[k],     e0 = csr_et[k];
    int s1 = csr_src[k + 1], e1 = csr_et[k + 1];
    F4 v0 = ld4(h2 + (size_t)s0 * 256 + lane * 4);
    F4 v1 = ld4(h2 + (size_t)s1 * 256 + lane * 4);
    F4 c0 = ld4(comp + (size_t)e0 * 4);
    F4 c1 = ld4(comp + (size_t)e1 * 4);
    acc[0].x += c0.x*v0.x + c1.x*v1.x; acc[0].y += c0.x*v0.y + c1.x*v1.y;
    acc[0].z += c0.x*v0.z + c1.x*v1.z; acc[0].w += c0.x*v0.w + c1.x*v1.w;
    acc[1].x += c0.y*v0.x + c1.y*v1.x; acc[1].y += c0.y*v0.y + c1.y*v1.y;
    acc[1].z += c0.y*v0.z + c1.y*v1.z; acc[1].w += c0.y*v0.w + c1.y*v1.w;
    acc[2].x += c0.z*v0.x + c1.z*v1.x; acc[2].y += c0.z*v0.y + c1.z*v1.y;
    acc[2].z += c0.z*v0.z + c1.z*v1.z; acc[2].w += c0.z*v0.w + c1.z*v1.w;
    acc[3].x += c0.w*v0.x + c1.w*v1.x; acc[3].y += c0.w*v0.y + c1.w*v1.y;
    acc[3].z += c0.w*v0.z + c1.w*v1.z; acc[3].w += c0.w*v0.w + c1.w*v1.w;
  }
  if (k < n1){
    int s = csr_src[k], e = csr_et[k];
    F4 v = ld4(h2 + (size_t)s * 256 + lane * 4);
    F4 cp = ld4(comp + (size_t)e * 4);
    acc[0].x += cp.x*v.x; acc[0].y += cp.x*v.y; acc[0].z += cp.x*v.z; acc[0].w += cp.x*v.w;
    acc[1].x += cp.y*v.x; acc[1].y += cp.y*v.y; acc[1].z += cp.y*v.z; acc[1].w += cp.y*v.w;
    acc[2].x += cp.z*v.x; acc[2].y += cp.z*v.y; acc[2].z += cp.z*v.z; acc[2].w += cp.z*v.w;
    acc[3].x += cp.w*v.x; acc[3].y += cp.w*v.y; acc[3].z += cp.w*v.z; acc[3].w += cp.w*v.w;
  }
  int dg = n1 - n0;
  float sc = 1.f / (float)(dg > 0 ? dg : 1);
  float* ar = agg + (size_t)wid * 1024 + lane * 4;
  #pragma unroll
  for (int b = 0; b < 4; b++)
    *(float4*)(ar + b * 256) = make_float4(acc[b].x * sc, acc[b].y * sc, acc[b].z * sc, acc[b].w * sc);
}

// ---------------- unified LDS-tiled GEMM ----------------
// OUT[n, cg*64 + c] = act( A1[n,:]@W1[:, cg*64+c] + A2[n,:]@W2[:, cg*64+c] + bias )
// block = 16 nodes x 64 cols (4 waves, 4 nodes/wave, acc[4]/thread).
// W tile [64][64] + A tile [16][64] staged in LDS (20KB).

template<bool ELU, bool ATT>
__global__ __launch_bounds__(256) void gemm_fused_kernel(
    const float* __restrict__ A1, int lda1, int K1,
    const float* __restrict__ W1, int ldw1,
    const float* __restrict__ A2, int lda2, int K2,
    const float* __restrict__ W2, int ldw2,
    const float* __restrict__ bias,
    const float* __restrict__ atts, const float* __restrict__ attd,
    float* __restrict__ Y, int ldy,
    float* __restrict__ as_, float* __restrict__ ad_,
    int nrows)
{
  __shared__ float Wl[64][64];
  __shared__ float Al[16][64];
  int t = threadIdx.x;
  int lane = t & 63, slot = t >> 6;
  int cg = blockIdx.y;
  int nbase = blockIdx.x * 16;
  float acc0 = 0.f, acc1 = 0.f, acc2 = 0.f, acc3 = 0.f;

  for (int seg = 0; seg < 2; seg++){
    const float* A = seg ? A2 : A1;
    const float* W = seg ? W2 : W1;
    int lda = seg ? lda2 : lda1;
    int ldw = seg ? ldw2 : ldw1;
    int K   = seg ? K2 : K1;
    if (A == nullptr || K <= 0) continue;
    for (int k0 = 0; k0 < K; k0 += 64){
      // stage W[k0+r][cg*64+c] -> Wl[r][c]  (zero-fill past K)
      #pragma unroll
      for (int i = 0; i < 4; i++){
        int e = i * 256 + t;           // float4 index within 64x64 tile
        int r = e >> 4, c4 = (e & 15) << 2;
        int kk = k0 + r;
        float4 v = make_float4(0.f, 0.f, 0.f, 0.f);
        if (kk < K) v = *(const float4*)(W + (size_t)kk * ldw + cg * 64 + c4);
        *(float4*)&Wl[r][c4] = v;
      }
      // stage A[nbase+r][k0+c] -> Al[r][c]
      {
        int r = t >> 4, c4 = (t & 15) << 2;
        int n = nbase + r, kk = k0 + c4;
        float4 v = make_float4(0.f, 0.f, 0.f, 0.f);
        if (n < nrows && kk < K) v = *(const float4*)(A + (size_t)n * lda + kk);
        *(float4*)&Al[r][c4] = v;
      }
      __syncthreads();
      for (int k = 0; k < 64; k += 4){
        float4 a0 = *(const float4*)&Al[slot * 4 + 0][k];
        float4 a1 = *(const float4*)&Al[slot * 4 + 1][k];
        float4 a2 = *(const float4*)&Al[slot * 4 + 2][k];
        float4 a3 = *(const float4*)&Al[slot * 4 + 3][k];
        const float* pa0 = (const float*)&a0;
        const float* pa1 = (const float*)&a1;
        const float* pa2 = (const float*)&a2;
        const float* pa3 = (const float*)&a3;
        #pragma unroll
        for (int i = 0; i < 4; i++){
          float w = Wl[k + i][lane];
          acc0 = fmaf(pa0[i], w, acc0);
          acc1 = fmaf(pa1[i], w, acc1);
          acc2 = fmaf(pa2[i], w, acc2);
          acc3 = fmaf(pa3[i], w, acc3);
        }
      }
      __syncthreads();
    }
  }

  float accs[4] = {acc0, acc1, acc2, acc3};
  int n0g = nbase + slot * 4;
  float b = bias ? bias[cg * 64 + lane] : 0.f;
  #pragma unroll
  for (int j = 0; j < 4; j++){
    int n = n0g + j;
    if (n < nrows){
      float y = accs[j] + b;
      if (ELU) y = eluf(y);
      Y[(size_t)n * ldy + cg * 64 + lane] = y;
    }
  }
  if (ATT){
    float ta = atts[cg * 64 + lane];
    float tb = attd[cg * 64 + lane];
    #pragma unroll
    for (int j = 0; j < 4; j++){
      float ps = accs[j] * ta;
      float pd = accs[j] * tb;
      #pragma unroll
      for (int o = 32; o; o >>= 1){ ps += __shfl_xor(ps, o); pd += __shfl_xor(pd, o); }
      int n = n0g + j;
      if (lane == 0 && n < nrows){ as_[n * 4 + cg] = ps; ad_[n * 4 + cg] = pd; }
    }
  }
}

// ---------------- GAT ----------------

// GAT1 softmax-aggregate. one wave per node; 16 edges x 4 heads of exp in parallel,
// broadcast p via shfl; gather = one b128/lane (full 1KB row per edge).
__global__ void gat1_agg_kernel(const float* __restrict__ hw, const float* __restrict__ as_,
                                const float* __restrict__ ad_, const float* __restrict__ bias,
                                const int* __restrict__ offs, const int* __restrict__ csr_src,
                                float* __restrict__ out){
  int wid  = (blockIdx.x * blockDim.x + threadIdx.x) >> 6;
  int lane = threadIdx.x & 63;
  if (wid >= NN) return;
  int n0 = offs[wid], n1 = offs[wid + 1];
  int h    = lane & 3;     // head this lane computes p for
  int hseg = lane >> 4;    // head segment this lane gathers
  float adn = ad_[wid * 4 + h];
  float es  = leakyf(as_[wid * 4 + h] + adn);
  // max over in-edges (+self), per head
  float m = es;
  for (int k = n0 + (lane >> 2); k < n1; k += 16){
    int s = csr_src[k];
    m = fmaxf(m, leakyf(as_[s * 4 + h] + adn));
  }
  #pragma unroll
  for (int o = 4; o < 64; o <<= 1) m = fmaxf(m, __shfl_xor(m, o));
  // main: chunks of 16 edges
  float den = 0.f;
  float4 acc = make_float4(0.f, 0.f, 0.f, 0.f);
  for (int base = n0; base < n1; base += 16){
    int k = base + (lane >> 2);
    int s = 0; float p = 0.f;
    if (k < n1){
      s = csr_src[k];
      p = expf(leakyf(as_[s * 4 + h] + adn) - m);
    }
    den += p;
    int cnt = min(16, n1 - base);
    for (int jj = 0; jj < cnt; jj++){
      float pj = __shfl(p, (jj << 2) | hseg);
      int  sj  = __shfl(s, (jj << 2));
      float4 v = *(const float4*)(hw + (size_t)sj * 256 + lane * 4);
      acc.x += pj * v.x; acc.y += pj * v.y; acc.z += pj * v.z; acc.w += pj * v.w;
    }
  }
  #pragma unroll
  for (int o = 4; o < 64; o <<= 1) den += __shfl_xor(den, o);
  float ps   = expf(es - m);
  float psh  = __shfl(ps, hseg);
  float denh = __shfl(den, hseg) + psh;
  float4 v = *(const float4*)(hw + (size_t)wid * 256 + lane * 4);
  acc.x += psh * v.x; acc.y += psh * v.y; acc.z += psh * v.z; acc.w += psh * v.w;
  float4 bb = *(const float4*)(bias + lane * 4);
  float4 o4;
  o4.x = eluf(acc.x / denh + bb.x);
  o4.y = eluf(acc.y / denh + bb.y);
  o4.z = eluf(acc.z / denh + bb.z);
  o4.w = eluf(acc.w / denh + bb.w);
  *(float4*)(out + (size_t)wid * 256 + lane * 4) = o4;
}

// hW2 = h3 @ Wg2 (64 -> 12), fused logits. one wave per node.
__global__ void gat_lin2_kernel(const float* __restrict__ h, const float* __restrict__ W,
                                const float* __restrict__ atts, const float* __restrict__ attd,
                                float* __restrict__ hw, float* __restrict__ as_, float* __restrict__ ad_){
  int wid  = (blockIdx.x * blockDim.x + threadIdx.x) >> 6;
  int lane = threadIdx.x & 63;
  if (wid >= NN) return;
  float acc = 0.f;
  if (lane < 12){
    const float* hr = h + (size_t)wid * 64;
    const float* Wc = W + lane;
    #pragma unroll 8
    for (int i = 0; i < 64; i++) acc += hr[i] * Wc[(size_t)i * 12];
    hw[(size_t)wid * 12 + lane] = acc;
  }
  float ts = (lane < 12) ? acc * atts[lane] : 0.f;
  float td = (lane < 12) ? acc * attd[lane] : 0.f;
  int b = (lane < 4) ? lane * 3 : 0;
  float s0 = __shfl(ts, b) + __shfl(ts, b + 1) + __shfl(ts, b + 2);
  float d0 = __shfl(td, b) + __shfl(td, b + 1) + __shfl(td, b + 2);
  if (lane < 4){ as_[wid * 4 + lane] = s0; ad_[wid * 4 + lane] = d0; }
}

// GAT2 (mean over heads) + mean over classes + tanh. one wave per node.
__global__ void gat2_final_kernel(const float* __restrict__ hw, const float* __restrict__ as_,
                                  const float* __restrict__ ad_, const float* __restrict__ bg2,
                                  const int* __restrict__ offs, const int* __restrict__ csr_src,
                                  float* __restrict__ out){
  int wid  = (blockIdx.x * blockDim.x + threadIdx.x) >> 6;
  int lane = threadIdx.x & 63;
  if (wid >= NN) return;
  int n0 = offs[wid], n1 = offs[wid + 1];
  F4 adn = ld4(ad_ + (size_t)wid * 4);
  F4 asn = ld4(as_ + (size_t)wid * 4);
  F4 es{leakyf(asn.x + adn.x), leakyf(asn.y + adn.y), leakyf(asn.z + adn.z), leakyf(asn.w + adn.w)};
  F4 m = es;
  for (int k = n0 + lane; k < n1; k += 64){
    int s = csr_src[k];
    F4 a = ld4(as_ + (size_t)s * 4);
    m.x = fmaxf(m.x, leakyf(a.x + adn.x));
    m.y = fmaxf(m.y, leakyf(a.y + adn.y));
    m.z = fmaxf(m.z, leakyf(a.z + adn.z));
    m.w = fmaxf(m.w, leakyf(a.w + adn.w));
  }
  #pragma unroll
  for (int o = 32; o; o >>= 1){
    m.x = fmaxf(m.x, __shfl_xor(m.x, o));
    m.y = fmaxf(m.y, __shfl_xor(m.y, o));
    m.z = fmaxf(m.z, __shfl_xor(m.z, o));
    m.w = fmaxf(m.w, __shfl_xor(m.w, o));
  }
  F4 ps{expf(es.x - m.x), expf(es.y - m.y), expf(es.z - m.z), expf(es.w - m.w)};
  float acc[12];
  #pragma unroll
  for (int j = 0; j < 12; j++) acc[j] = 0.f;
  F4 denp{0.f, 0.f, 0.f, 0.f};
  for (int k = n0 + lane; k < n1; k += 64){
    int s = csr_src[k];
    F4 a = ld4(as_ + (size_t)s * 4);
    F4 p{expf(leakyf(a.x + adn.x) - m.x), expf(leakyf(a.y + adn.y) - m.y),
         expf(leakyf(a.z + adn.z) - m.z), expf(leakyf(a.w + adn.w) - m.w)};
    denp.x += p.x; denp.y += p.y; denp.z += p.z; denp.w += p.w;
    const float* hb = hw + (size_t)s * 12;
    F4 h0 = ld4(hb), h1 = ld4(hb + 4), h2 = ld4(hb + 8);
    acc[0] += p.x * h0.x; acc[1]  += p.x * h0.y; acc[2]  += p.x * h0.z;
    acc[3] += p.y * h0.w; acc[4]  += p.y * h1.x; acc[5]  += p.y * h1.y;
    acc[6] += p.z * h1.z; acc[7]  += p.z * h1.w; acc[8]  += p.z * h2.x;
    acc[9] += p.w * h2.y; acc[10] += p.w * h2.z; acc[11] += p.w * h2.w;
  }
  #pragma unroll
  for (int o = 32; o; o >>= 1){
    denp.x += __shfl_xor(denp.x, o);
    denp.y += __shfl_xor(denp.y, o);
    denp.z += __shfl_xor(denp.z, o);
    denp.w += __shfl_xor(denp.w, o);
    #pragma unroll
    for (int j = 0; j < 12; j++) acc[j] += __shfl_xor(acc[j], o);
  }
  if (lane == 0){
    const float* hn = hw + (size_t)wid * 12;
    float dn[4]  = {denp.x + ps.x, denp.y + ps.y, denp.z + ps.z, denp.w + ps.w};
    float psv[4] = {ps.x, ps.y, ps.z, ps.w};
    float tot = 0.f;
    #pragma unroll
    for (int h_ = 0; h_ < 4; h_++){
      #pragma unroll
      for (int c = 0; c < 3; c++){
        float num = acc[h_ * 3 + c] + psv[h_] * hn[h_ * 3 + c];
        tot += num / dn[h_];
      }
    }
    tot = tot / 12.f + (bg2[0] + bg2[1] + bg2[2]) / 3.f;
    out[wid] = tanhf(tot);
  }
}

// ---------------- launch ----------------

extern "C" void kernel_launch(void* const* d_in, const int* in_sizes, int n_in,
                              void* d_out, int out_size, void* d_ws, size_t ws_size,
                              hipStream_t stream){
  const float* x      = (const float*)d_in[0];
  const int*   ei     = (const int*)d_in[1];
  const int*   et     = (const int*)d_in[2];
  const float* basis1 = (const float*)d_in[3];
  const float* comp1  = (const float*)d_in[4];
  const float* root1  = (const float*)d_in[5];
  const float* brg1   = (const float*)d_in[6];
  const float* Wg1    = (const float*)d_in[7];
  const float* atts1  = (const float*)d_in[8];
  const float* attd1  = (const float*)d_in[9];
  const float* bg1    = (const float*)d_in[10];
  const float* basis2 = (const float*)d_in[11];
  const float* comp2  = (const float*)d_in[12];
  const float* root2  = (const float*)d_in[13];
  const float* brg2   = (const float*)d_in[14];
  const float* Wg2    = (const float*)d_in[15];
  const float* atts2  = (const float*)d_in[16];
  const float* attd2  = (const float*)d_in[17];
  const float* bg2    = (const float*)d_in[18];
  float* out = (float*)d_out;

  const int* src = ei;
  const int* dst = ei + NE;

  char* ws = (char*)d_ws;
  size_t off = 0;
  auto alloc = [&](size_t bytes) -> void* {
    void* p = ws + off;
    off = (off + bytes + 255) & ~(size_t)255;
    return p;
  };
  // persistent
  int*   deg     = (int*)alloc((size_t)NN * 4);
  int*   cursor  = (int*)alloc((size_t)NN * 4);
  int*   offs    = (int*)alloc((size_t)(NN + 1) * 4);
  int*   bsum    = (int*)alloc((size_t)256 * 4);
  int*   csr_src = (int*)alloc((size_t)NE * 4);
  int*   csr_et  = (int*)alloc((size_t)NE * 4);
  float* h1      = (float*)alloc((size_t)NN * 64 * 4);
  float* h2      = (float*)alloc((size_t)NN * 256 * 4);
  float* h3      = (float*)alloc((size_t)NN * 64 * 4);
  float* hw2     = (float*)alloc((size_t)NN * 12 * 4);
  float* as1     = (float*)alloc((size_t)NN * 4 * 4);
  float* ad1     = (float*)alloc((size_t)NN * 4 * 4);
  float* as2     = (float*)alloc((size_t)NN * 4 * 4);
  float* ad2     = (float*)alloc((size_t)NN * 4 * 4);
  // scratch union: agg1[NN*128] -> hW1[NN*256] -> agg3[HALF*1024]
  float* S       = (float*)alloc((size_t)HALF * 1024 * 4);
  float* agg1    = S;
  float* hW1     = S;
  float* agg3    = S;
  (void)ws_size; (void)n_in; (void)in_sizes; (void)out_size;

  const int BLK = 256;
  int gridN  = (NN + BLK - 1) / BLK;    // 118
  int gridE  = (NE + BLK - 1) / BLK;
  int gridW  = (NN + 3) / 4;            // 4 waves/block, 1 node/wave
  int gridWH = (HALF + 3) / 4;

  // CSR build
  zero_int_kernel<<<gridN, BLK, 0, stream>>>(deg, NN);
  zero_int_kernel<<<gridN, BLK, 0, stream>>>(cursor, NN);
  count_kernel<<<gridE, BLK, 0, stream>>>(dst, deg, NE);
  scan1_kernel<<<gridN, BLK, 0, stream>>>(deg, offs, bsum);
  scan2_kernel<<<1, BLK, 0, stream>>>(bsum, gridN);
  scan3_kernel<<<gridN, BLK, 0, stream>>>(bsum, offs);
  scatter_kernel<<<gridE, BLK, 0, stream>>>(src, dst, et, offs, cursor, csr_src, csr_et, NE);

  // Layer 1: RGCN (32 -> 64) + elu: agg-first, fused GEMM (basis + root + bias + elu)
  agg1_kernel<<<gridW, BLK, 0, stream>>>(x, comp1, offs, csr_src, csr_et, agg1);
  gemm_fused_kernel<true, false><<<dim3((NN + 15) / 16, 1), BLK, 0, stream>>>(
      agg1, 128, 128, basis1, 64,
      x, 32, 32, root1, 64,
      brg1, nullptr, nullptr, h1, 64, nullptr, nullptr, NN);

  // Layer 2: GAT (64 -> 256 concat): linear + fused attention logits, then softmax-agg
  gemm_fused_kernel<false, true><<<dim3((NN + 15) / 16, 4), BLK, 0, stream>>>(
      h1, 64, 64, Wg1, 256,
      nullptr, 0, 0, nullptr, 0,
      nullptr, atts1, attd1, hW1, 256, as1, ad1, NN);
  gat1_agg_kernel<<<gridW, BLK, 0, stream>>>(hW1, as1, ad1, bg1, offs, csr_src, h2);

  // Layer 3: RGCN (256 -> 64) + elu: agg-first, two node-halves
  for (int half = 0; half < 2; half++){
    int base = half * HALF;
    agg3_kernel<<<gridWH, BLK, 0, stream>>>(h2, comp2, offs, csr_src, csr_et, agg3, base, HALF);
    gemm_fused_kernel<true, false><<<dim3((HALF + 15) / 16, 1), BLK, 0, stream>>>(
        agg3, 1024, 1024, basis2, 64,
        h2 + (size_t)base * 256, 256, 256, root2, 64,
        brg2, nullptr, nullptr, h3 + (size_t)base * 64, 64, nullptr, nullptr, HALF);
  }

  // Layer 4: GAT (64 -> 4x3, mean heads) + mean classes + tanh
  gat_lin2_kernel<<<gridW, BLK, 0, stream>>>(h3, Wg2, atts2, attd2, hw2, as2, ad2);
  gat2_final_kernel<<<gridW, BLK, 0, stream>>>(hw2, as2, ad2, bg2, offs, csr_src, out);
}

// Round 6
// 543.985 us; speedup vs baseline: 1.8952x; 1.0522x over previous
//
#include <hip/hip_runtime.h>
#include <cstdint>
#include <cstddef>

#define NN 30000
#define NE 480000
#define HALF 15000

__device__ __forceinline__ float leakyf(float x){ return x > 0.f ? x : 0.2f * x; }
__device__ __forceinline__ float eluf(float x){ return x > 0.f ? x : expm1f(x); }

struct F4 { float x, y, z, w; };

__device__ __forceinline__ F4 ld4(const float* p){
  float4 v = *(const float4*)p;
  return F4{v.x, v.y, v.z, v.w};
}

// ---------------- CSR build ----------------

__global__ void zero_int_kernel(int* __restrict__ p, int n){
  int i = blockIdx.x * blockDim.x + threadIdx.x;
  if (i < n) p[i] = 0;
}

__global__ void count_kernel(const int* __restrict__ dst, int* __restrict__ deg, int E){
  int i = blockIdx.x * blockDim.x + threadIdx.x;
  if (i < E) atomicAdd(&deg[dst[i]], 1);
}

__global__ void scan1_kernel(const int* __restrict__ deg, int* __restrict__ offs,
                             int* __restrict__ bsum){
  __shared__ int sh[256];
  int blk = blockIdx.x, t = threadIdx.x, i = blk * 256 + t;
  int v = (i < NN) ? deg[i] : 0;
  sh[t] = v; __syncthreads();
  for (int o = 1; o < 256; o <<= 1){
    int tv = (t >= o) ? sh[t - o] : 0;
    __syncthreads();
    sh[t] += tv;
    __syncthreads();
  }
  if (i < NN) offs[i + 1] = sh[t];
  if (t == 255) bsum[blk] = sh[255];
}

__global__ void scan2_kernel(int* __restrict__ bsum, int nb){
  __shared__ int sh[256];
  int t = threadIdx.x;
  int v = (t < nb) ? bsum[t] : 0;
  sh[t] = v; __syncthreads();
  for (int o = 1; o < 256; o <<= 1){
    int tv = (t >= o) ? sh[t - o] : 0;
    __syncthreads();
    sh[t] += tv;
    __syncthreads();
  }
  if (t < nb) bsum[t] = sh[t];
}

__global__ void scan3_kernel(const int* __restrict__ bsum, int* __restrict__ offs){
  int i = blockIdx.x * 256 + threadIdx.x;
  if (i == 0) offs[0] = 0;
  if (i < NN){
    int blk = i >> 8;
    int add = blk ? bsum[blk - 1] : 0;
    offs[i + 1] += add;
  }
}

__global__ void scatter_kernel(const int* __restrict__ src, const int* __restrict__ dst,
                               const int* __restrict__ et, const int* __restrict__ offs,
                               int* __restrict__ cursor, int* __restrict__ csr_src,
                               int* __restrict__ csr_et, int E){
  int i = blockIdx.x * blockDim.x + threadIdx.x;
  if (i < E){
    int d = dst[i];
    int pos = offs[d] + atomicAdd(&cursor[d], 1);
    csr_src[pos] = src[i];
    csr_et[pos]  = et[i];
  }
}

// ---------------- basis-space aggregation ----------------

__global__ void agg1_kernel(const float* __restrict__ x, const float* __restrict__ comp,
                            const int* __restrict__ offs, const int* __restrict__ csr_src,
                            const int* __restrict__ csr_et, float* __restrict__ agg){
  int wid  = (blockIdx.x * blockDim.x + threadIdx.x) >> 6;
  int lane = threadIdx.x & 63;
  if (wid >= NN) return;
  int c = lane & 31, half = lane >> 5;
  int n0 = offs[wid], n1 = offs[wid + 1];
  float a0 = 0.f, a1 = 0.f, a2 = 0.f, a3 = 0.f;
  for (int k = n0 + half; k < n1; k += 2){
    int s = csr_src[k], e = csr_et[k];
    float v = x[(size_t)s * 32 + c];
    F4 cp = ld4(comp + (size_t)e * 4);
    a0 += cp.x * v; a1 += cp.y * v; a2 += cp.z * v; a3 += cp.w * v;
  }
  a0 += __shfl_xor(a0, 32);
  a1 += __shfl_xor(a1, 32);
  a2 += __shfl_xor(a2, 32);
  a3 += __shfl_xor(a3, 32);
  int dg = n1 - n0;
  float sc = 1.f / (float)(dg > 0 ? dg : 1);
  if (lane < 32){
    float* ar = agg + (size_t)wid * 128 + c;
    ar[0]  = a0 * sc;
    ar[32] = a1 * sc;
    ar[64] = a2 * sc;
    ar[96] = a3 * sc;
  }
}

__global__ void agg3_kernel(const float* __restrict__ h2, const float* __restrict__ comp,
                            const int* __restrict__ offs, const int* __restrict__ csr_src,
                            const int* __restrict__ csr_et, float* __restrict__ agg,
                            int node_base, int count){
  int wid  = (blockIdx.x * blockDim.x + threadIdx.x) >> 6;
  int lane = threadIdx.x & 63;
  if (wid >= count) return;
  int node = node_base + wid;
  int n0 = offs[node], n1 = offs[node + 1];
  F4 acc[4];
  #pragma unroll
  for (int b = 0; b < 4; b++) acc[b] = F4{0.f, 0.f, 0.f, 0.f};
  int k = n0;
  for (; k + 1 < n1; k += 2){
    int s0 = csr_src[k],     e0 = csr_et[k];
    int s1 = csr_src[k + 1], e1 = csr_et[k + 1];
    F4 v0 = ld4(h2 + (size_t)s0 * 256 + lane * 4);
    F4 v1 = ld4(h2 + (size_t)s1 * 256 + lane * 4);
    F4 c0 = ld4(comp + (size_t)e0 * 4);
    F4 c1 = ld4(comp + (size_t)e1 * 4);
    acc[0].x += c0.x*v0.x + c1.x*v1.x; acc[0].y += c0.x*v0.y + c1.x*v1.y;
    acc[0].z += c0.x*v0.z + c1.x*v1.z; acc[0].w += c0.x*v0.w + c1.x*v1.w;
    acc[1].x += c0.y*v0.x + c1.y*v1.x; acc[1].y += c0.y*v0.y + c1.y*v1.y;
    acc[1].z += c0.y*v0.z + c1.y*v1.z; acc[1].w += c0.y*v0.w + c1.y*v1.w;
    acc[2].x += c0.z*v0.x + c1.z*v1.x; acc[2].y += c0.z*v0.y + c1.z*v1.y;
    acc[2].z += c0.z*v0.z + c1.z*v1.z; acc[2].w += c0.z*v0.w + c1.z*v1.w;
    acc[3].x += c0.w*v0.x + c1.w*v1.x; acc[3].y += c0.w*v0.y + c1.w*v1.y;
    acc[3].z += c0.w*v0.z + c1.w*v1.z; acc[3].w += c0.w*v0.w + c1.w*v1.w;
  }
  if (k < n1){
    int s = csr_src[k], e = csr_et[k];
    F4 v = ld4(h2 + (size_t)s * 256 + lane * 4);
    F4 cp = ld4(comp + (size_t)e * 4);
    acc[0].x += cp.x*v.x; acc[0].y += cp.x*v.y; acc[0].z += cp.x*v.z; acc[0].w += cp.x*v.w;
    acc[1].x += cp.y*v.x; acc[1].y += cp.y*v.y; acc[1].z += cp.y*v.z; acc[1].w += cp.y*v.w;
    acc[2].x += cp.z*v.x; acc[2].y += cp.z*v.y; acc[2].z += cp.z*v.z; acc[2].w += cp.z*v.w;
    acc[3].x += cp.w*v.x; acc[3].y += cp.w*v.y; acc[3].z += cp.w*v.z; acc[3].w += cp.w*v.w;
  }
  int dg = n1 - n0;
  float sc = 1.f / (float)(dg > 0 ? dg : 1);
  float* ar = agg + (size_t)wid * 1024 + lane * 4;
  #pragma unroll
  for (int b = 0; b < 4; b++)
    *(float4*)(ar + b * 256) = make_float4(acc[b].x * sc, acc[b].y * sc, acc[b].z * sc, acc[b].w * sc);
}

// ---------------- 64x64-tile fused GEMM, 4x4 register microtile ----------------
// OUT[n, cg*64+c] = act( A1[n,:]@W1[:, cg*64+c] + A2[n,:]@W2[:, cg*64+c] + bias )
// 256 threads = 16 (tc) x 16 (tr); thread owns rows tr*4..+3, cols tc*4..+3.
// A staged TRANSPOSED (At[k][r]), W staged Wl[k][c]; inner loop = 2 b128 + 16 FMA per k.

template<bool ELU, bool ATT>
__global__ __launch_bounds__(256) void gemm64_kernel(
    const float* __restrict__ A1, int lda1, int K1,
    const float* __restrict__ W1, int ldw1,
    const float* __restrict__ A2, int lda2, int K2,
    const float* __restrict__ W2, int ldw2,
    const float* __restrict__ bias,
    const float* __restrict__ atts, const float* __restrict__ attd,
    float* __restrict__ Y, int ldy,
    float* __restrict__ as_, float* __restrict__ ad_,
    int nrows)
{
  __shared__ float At[64][72];
  __shared__ float Wl[64][72];
  int t = threadIdx.x;
  int tc = t & 15, tr = t >> 4;
  int cg = blockIdx.y;
  int nbase = blockIdx.x * 64;
  float acc[4][4];
  #pragma unroll
  for (int j = 0; j < 4; j++)
    #pragma unroll
    for (int i = 0; i < 4; i++) acc[j][i] = 0.f;

  for (int seg = 0; seg < 2; seg++){
    const float* A = seg ? A2 : A1;
    const float* W = seg ? W2 : W1;
    int lda = seg ? lda2 : lda1;
    int ldw = seg ? ldw2 : ldw1;
    int K   = seg ? K2 : K1;
    if (A == nullptr || K <= 0) continue;
    for (int k0 = 0; k0 < K; k0 += 64){
      // stage W[k0+kk][cg*64+c] -> Wl[kk][c]; zero-fill past K
      #pragma unroll
      for (int i = 0; i < 4; i++){
        int e = i * 256 + t;
        int kk = e >> 4, c4 = (e & 15) << 2;
        float4 v = make_float4(0.f, 0.f, 0.f, 0.f);
        if (k0 + kk < K) v = *(const float4*)(W + (size_t)(k0 + kk) * ldw + cg * 64 + c4);
        *(float4*)&Wl[kk][c4] = v;
      }
      // stage A[nbase+r][k0+kk] -> At[kk][r] (transposed); zero-fill
      {
        int r = t >> 2;
        int n = nbase + r;
        #pragma unroll
        for (int i = 0; i < 4; i++){
          int c4 = ((t & 3) << 2) + (i << 4);
          float4 v = make_float4(0.f, 0.f, 0.f, 0.f);
          if (n < nrows && k0 + c4 < K) v = *(const float4*)(A + (size_t)n * lda + k0 + c4);
          At[c4 + 0][r] = v.x;
          At[c4 + 1][r] = v.y;
          At[c4 + 2][r] = v.z;
          At[c4 + 3][r] = v.w;
        }
      }
      __syncthreads();
      #pragma unroll 8
      for (int k = 0; k < 64; k++){
        float4 av = *(const float4*)&At[k][tr * 4];
        float4 wv = *(const float4*)&Wl[k][tc * 4];
        const float* pa = (const float*)&av;
        const float* pw = (const float*)&wv;
        #pragma unroll
        for (int j = 0; j < 4; j++)
          #pragma unroll
          for (int i = 0; i < 4; i++)
            acc[j][i] = fmaf(pa[j], pw[i], acc[j][i]);
      }
      __syncthreads();
    }
  }

  // epilogue
  float b0 = 0.f, b1 = 0.f, b2 = 0.f, b3 = 0.f;
  if (bias){
    b0 = bias[cg * 64 + tc * 4 + 0];
    b1 = bias[cg * 64 + tc * 4 + 1];
    b2 = bias[cg * 64 + tc * 4 + 2];
    b3 = bias[cg * 64 + tc * 4 + 3];
  }
  #pragma unroll
  for (int j = 0; j < 4; j++){
    int n = nbase + tr * 4 + j;
    if (n < nrows){
      float y0 = acc[j][0] + b0, y1 = acc[j][1] + b1, y2 = acc[j][2] + b2, y3 = acc[j][3] + b3;
      if (ELU){ y0 = eluf(y0); y1 = eluf(y1); y2 = eluf(y2); y3 = eluf(y3); }
      *(float4*)(Y + (size_t)n * ldy + cg * 64 + tc * 4) = make_float4(y0, y1, y2, y3);
    }
  }
  if (ATT){
    float ta0 = atts[cg * 64 + tc * 4 + 0], ta1 = atts[cg * 64 + tc * 4 + 1];
    float ta2 = atts[cg * 64 + tc * 4 + 2], ta3 = atts[cg * 64 + tc * 4 + 3];
    float tb0 = attd[cg * 64 + tc * 4 + 0], tb1 = attd[cg * 64 + tc * 4 + 1];
    float tb2 = attd[cg * 64 + tc * 4 + 2], tb3 = attd[cg * 64 + tc * 4 + 3];
    #pragma unroll
    for (int j = 0; j < 4; j++){
      float ps = acc[j][0]*ta0 + acc[j][1]*ta1 + acc[j][2]*ta2 + acc[j][3]*ta3;
      float pd = acc[j][0]*tb0 + acc[j][1]*tb1 + acc[j][2]*tb2 + acc[j][3]*tb3;
      #pragma unroll
      for (int o = 8; o; o >>= 1){ ps += __shfl_xor(ps, o); pd += __shfl_xor(pd, o); }
      int n = nbase + tr * 4 + j;
      if (tc == 0 && n < nrows){ as_[n * 4 + cg] = ps; ad_[n * 4 + cg] = pd; }
    }
  }
}

// ---------------- GAT ----------------

// GAT1 softmax-aggregate. one wave per node; 16 edges x 4 heads of exp in parallel,
// broadcast p via shfl; gather = one b128/lane (full 1KB row per edge).
__global__ void gat1_agg_kernel(const float* __restrict__ hw, const float* __restrict__ as_,
                                const float* __restrict__ ad_, const float* __restrict__ bias,
                                const int* __restrict__ offs, const int* __restrict__ csr_src,
                                float* __restrict__ out){
  int wid  = (blockIdx.x * blockDim.x + threadIdx.x) >> 6;
  int lane = threadIdx.x & 63;
  if (wid >= NN) return;
  int n0 = offs[wid], n1 = offs[wid + 1];
  int h    = lane & 3;
  int hseg = lane >> 4;
  float adn = ad_[wid * 4 + h];
  float es  = leakyf(as_[wid * 4 + h] + adn);
  float m = es;
  for (int k = n0 + (lane >> 2); k < n1; k += 16){
    int s = csr_src[k];
    m = fmaxf(m, leakyf(as_[s * 4 + h] + adn));
  }
  #pragma unroll
  for (int o = 4; o < 64; o <<= 1) m = fmaxf(m, __shfl_xor(m, o));
  float den = 0.f;
  float4 acc = make_float4(0.f, 0.f, 0.f, 0.f);
  for (int base = n0; base < n1; base += 16){
    int k = base + (lane >> 2);
    int s = 0; float p = 0.f;
    if (k < n1){
      s = csr_src[k];
      p = expf(leakyf(as_[s * 4 + h] + adn) - m);
    }
    den += p;
    int cnt = min(16, n1 - base);
    for (int jj = 0; jj < cnt; jj++){
      float pj = __shfl(p, (jj << 2) | hseg);
      int  sj  = __shfl(s, (jj << 2));
      float4 v = *(const float4*)(hw + (size_t)sj * 256 + lane * 4);
      acc.x += pj * v.x; acc.y += pj * v.y; acc.z += pj * v.z; acc.w += pj * v.w;
    }
  }
  #pragma unroll
  for (int o = 4; o < 64; o <<= 1) den += __shfl_xor(den, o);
  float ps   = expf(es - m);
  float psh  = __shfl(ps, hseg);
  float denh = __shfl(den, hseg) + psh;
  float4 v = *(const float4*)(hw + (size_t)wid * 256 + lane * 4);
  acc.x += psh * v.x; acc.y += psh * v.y; acc.z += psh * v.z; acc.w += psh * v.w;
  float4 bb = *(const float4*)(bias + lane * 4);
  float4 o4;
  o4.x = eluf(acc.x / denh + bb.x);
  o4.y = eluf(acc.y / denh + bb.y);
  o4.z = eluf(acc.z / denh + bb.z);
  o4.w = eluf(acc.w / denh + bb.w);
  *(float4*)(out + (size_t)wid * 256 + lane * 4) = o4;
}

// hW2 = h3 @ Wg2 (64 -> 12), fused logits. one wave per node.
__global__ void gat_lin2_kernel(const float* __restrict__ h, const float* __restrict__ W,
                                const float* __restrict__ atts, const float* __restrict__ attd,
                                float* __restrict__ hw, float* __restrict__ as_, float* __restrict__ ad_){
  int wid  = (blockIdx.x * blockDim.x + threadIdx.x) >> 6;
  int lane = threadIdx.x & 63;
  if (wid >= NN) return;
  float acc = 0.f;
  if (lane < 12){
    const float* hr = h + (size_t)wid * 64;
    const float* Wc = W + lane;
    #pragma unroll 8
    for (int i = 0; i < 64; i++) acc += hr[i] * Wc[(size_t)i * 12];
    hw[(size_t)wid * 12 + lane] = acc;
  }
  float ts = (lane < 12) ? acc * atts[lane] : 0.f;
  float td = (lane < 12) ? acc * attd[lane] : 0.f;
  int b = (lane < 4) ? lane * 3 : 0;
  float s0 = __shfl(ts, b) + __shfl(ts, b + 1) + __shfl(ts, b + 2);
  float d0 = __shfl(td, b) + __shfl(td, b + 1) + __shfl(td, b + 2);
  if (lane < 4){ as_[wid * 4 + lane] = s0; ad_[wid * 4 + lane] = d0; }
}

// GAT2 (mean over heads) + mean over classes + tanh. one wave per node.
__global__ void gat2_final_kernel(const float* __restrict__ hw, const float* __restrict__ as_,
                                  const float* __restrict__ ad_, const float* __restrict__ bg2,
                                  const int* __restrict__ offs, const int* __restrict__ csr_src,
                                  float* __restrict__ out){
  int wid  = (blockIdx.x * blockDim.x + threadIdx.x) >> 6;
  int lane = threadIdx.x & 63;
  if (wid >= NN) return;
  int n0 = offs[wid], n1 = offs[wid + 1];
  F4 adn = ld4(ad_ + (size_t)wid * 4);
  F4 asn = ld4(as_ + (size_t)wid * 4);
  F4 es{leakyf(asn.x + adn.x), leakyf(asn.y + adn.y), leakyf(asn.z + adn.z), leakyf(asn.w + adn.w)};
  F4 m = es;
  for (int k = n0 + lane; k < n1; k += 64){
    int s = csr_src[k];
    F4 a = ld4(as_ + (size_t)s * 4);
    m.x = fmaxf(m.x, leakyf(a.x + adn.x));
    m.y = fmaxf(m.y, leakyf(a.y + adn.y));
    m.z = fmaxf(m.z, leakyf(a.z + adn.z));
    m.w = fmaxf(m.w, leakyf(a.w + adn.w));
  }
  #pragma unroll
  for (int o = 32; o; o >>= 1){
    m.x = fmaxf(m.x, __shfl_xor(m.x, o));
    m.y = fmaxf(m.y, __shfl_xor(m.y, o));
    m.z = fmaxf(m.z, __shfl_xor(m.z, o));
    m.w = fmaxf(m.w, __shfl_xor(m.w, o));
  }
  F4 ps{expf(es.x - m.x), expf(es.y - m.y), expf(es.z - m.z), expf(es.w - m.w)};
  float acc[12];
  #pragma unroll
  for (int j = 0; j < 12; j++) acc[j] = 0.f;
  F4 denp{0.f, 0.f, 0.f, 0.f};
  for (int k = n0 + lane; k < n1; k += 64){
    int s = csr_src[k];
    F4 a = ld4(as_ + (size_t)s * 4);
    F4 p{expf(leakyf(a.x + adn.x) - m.x), expf(leakyf(a.y + adn.y) - m.y),
         expf(leakyf(a.z + adn.z) - m.z), expf(leakyf(a.w + adn.w) - m.w)};
    denp.x += p.x; denp.y += p.y; denp.z += p.z; denp.w += p.w;
    const float* hb = hw + (size_t)s * 12;
    F4 h0 = ld4(hb), h1 = ld4(hb + 4), h2 = ld4(hb + 8);
    acc[0] += p.x * h0.x; acc[1]  += p.x * h0.y; acc[2]  += p.x * h0.z;
    acc[3] += p.y * h0.w; acc[4]  += p.y * h1.x; acc[5]  += p.y * h1.y;
    acc[6] += p.z * h1.z; acc[7]  += p.z * h1.w; acc[8]  += p.z * h2.x;
    acc[9] += p.w * h2.y; acc[10] += p.w * h2.z; acc[11] += p.w * h2.w;
  }
  #pragma unroll
  for (int o = 32; o; o >>= 1){
    denp.x += __shfl_xor(denp.x, o);
    denp.y += __shfl_xor(denp.y, o);
    denp.z += __shfl_xor(denp.z, o);
    denp.w += __shfl_xor(denp.w, o);
    #pragma unroll
    for (int j = 0; j < 12; j++) acc[j] += __shfl_xor(acc[j], o);
  }
  if (lane == 0){
    const float* hn = hw + (size_t)wid * 12;
    float dn[4]  = {denp.x + ps.x, denp.y + ps.y, denp.z + ps.z, denp.w + ps.w};
    float psv[4] = {ps.x, ps.y, ps.z, ps.w};
    float tot = 0.f;
    #pragma unroll
    for (int h_ = 0; h_ < 4; h_++){
      #pragma unroll
      for (int c = 0; c < 3; c++){
        float num = acc[h_ * 3 + c] + psv[h_] * hn[h_ * 3 + c];
        tot += num / dn[h_];
      }
    }
    tot = tot / 12.f + (bg2[0] + bg2[1] + bg2[2]) / 3.f;
    out[wid] = tanhf(tot);
  }
}

// ---------------- launch ----------------

extern "C" void kernel_launch(void* const* d_in, const int* in_sizes, int n_in,
                              void* d_out, int out_size, void* d_ws, size_t ws_size,
                              hipStream_t stream){
  const float* x      = (const float*)d_in[0];
  const int*   ei     = (const int*)d_in[1];
  const int*   et     = (const int*)d_in[2];
  const float* basis1 = (const float*)d_in[3];
  const float* comp1  = (const float*)d_in[4];
  const float* root1  = (const float*)d_in[5];
  const float* brg1   = (const float*)d_in[6];
  const float* Wg1    = (const float*)d_in[7];
  const float* atts1  = (const float*)d_in[8];
  const float* attd1  = (const float*)d_in[9];
  const float* bg1    = (const float*)d_in[10];
  const float* basis2 = (const float*)d_in[11];
  const float* comp2  = (const float*)d_in[12];
  const float* root2  = (const float*)d_in[13];
  const float* brg2   = (const float*)d_in[14];
  const float* Wg2    = (const float*)d_in[15];
  const float* atts2  = (const float*)d_in[16];
  const float* attd2  = (const float*)d_in[17];
  const float* bg2    = (const float*)d_in[18];
  float* out = (float*)d_out;

  const int* src = ei;
  const int* dst = ei + NE;

  char* ws = (char*)d_ws;
  size_t off = 0;
  auto alloc = [&](size_t bytes) -> void* {
    void* p = ws + off;
    off = (off + bytes + 255) & ~(size_t)255;
    return p;
  };
  // persistent
  int*   deg     = (int*)alloc((size_t)NN * 4);
  int*   cursor  = (int*)alloc((size_t)NN * 4);
  int*   offs    = (int*)alloc((size_t)(NN + 1) * 4);
  int*   bsum    = (int*)alloc((size_t)256 * 4);
  int*   csr_src = (int*)alloc((size_t)NE * 4);
  int*   csr_et  = (int*)alloc((size_t)NE * 4);
  float* h1      = (float*)alloc((size_t)NN * 64 * 4);
  float* h2      = (float*)alloc((size_t)NN * 256 * 4);
  float* h3      = (float*)alloc((size_t)NN * 64 * 4);
  float* hw2     = (float*)alloc((size_t)NN * 12 * 4);
  float* as1     = (float*)alloc((size_t)NN * 4 * 4);
  float* ad1     = (float*)alloc((size_t)NN * 4 * 4);
  float* as2     = (float*)alloc((size_t)NN * 4 * 4);
  float* ad2     = (float*)alloc((size_t)NN * 4 * 4);
  // scratch union: agg1[NN*128] -> hW1[NN*256] -> agg3[HALF*1024]
  float* S       = (float*)alloc((size_t)HALF * 1024 * 4);
  float* agg1    = S;
  float* hW1     = S;
  float* agg3    = S;
  (void)ws_size; (void)n_in; (void)in_sizes; (void)out_size;

  const int BLK = 256;
  int gridN  = (NN + BLK - 1) / BLK;
  int gridE  = (NE + BLK - 1) / BLK;
  int gridW  = (NN + 3) / 4;
  int gridWH = (HALF + 3) / 4;
  int gridM  = (NN + 63) / 64;          // 64-row GEMM tiles
  int gridMH = (HALF + 63) / 64;

  // CSR build
  zero_int_kernel<<<gridN, BLK, 0, stream>>>(deg, NN);
  zero_int_kernel<<<gridN, BLK, 0, stream>>>(cursor, NN);
  count_kernel<<<gridE, BLK, 0, stream>>>(dst, deg, NE);
  scan1_kernel<<<gridN, BLK, 0, stream>>>(deg, offs, bsum);
  scan2_kernel<<<1, BLK, 0, stream>>>(bsum, gridN);
  scan3_kernel<<<gridN, BLK, 0, stream>>>(bsum, offs);
  scatter_kernel<<<gridE, BLK, 0, stream>>>(src, dst, et, offs, cursor, csr_src, csr_et, NE);

  // Layer 1: RGCN (32 -> 64) + elu: agg-first, fused GEMM (basis + root + bias + elu)
  agg1_kernel<<<gridW, BLK, 0, stream>>>(x, comp1, offs, csr_src, csr_et, agg1);
  gemm64_kernel<true, false><<<dim3(gridM, 1), BLK, 0, stream>>>(
      agg1, 128, 128, basis1, 64,
      x, 32, 32, root1, 64,
      brg1, nullptr, nullptr, h1, 64, nullptr, nullptr, NN);

  // Layer 2: GAT (64 -> 256 concat): linear + fused attention logits, then softmax-agg
  gemm64_kernel<false, true><<<dim3(gridM, 4), BLK, 0, stream>>>(
      h1, 64, 64, Wg1, 256,
      nullptr, 0, 0, nullptr, 0,
      nullptr, atts1, attd1, hW1, 256, as1, ad1, NN);
  gat1_agg_kernel<<<gridW, BLK, 0, stream>>>(hW1, as1, ad1, bg1, offs, csr_src, h2);

  // Layer 3: RGCN (256 -> 64) + elu: agg-first, two node-halves
  for (int half = 0; half < 2; half++){
    int base = half * HALF;
    agg3_kernel<<<gridWH, BLK, 0, stream>>>(h2, comp2, offs, csr_src, csr_et, agg3, base, HALF);
    gemm64_kernel<true, false><<<dim3(gridMH, 1), BLK, 0, stream>>>(
        agg3, 1024, 1024, basis2, 64,
        h2 + (size_t)base * 256, 256, 256, root2, 64,
        brg2, nullptr, nullptr, h3 + (size_t)base * 64, 64, nullptr, nullptr, HALF);
  }

  // Layer 4: GAT (64 -> 4x3, mean heads) + mean classes + tanh
  gat_lin2_kernel<<<gridW, BLK, 0, stream>>>(h3, Wg2, atts2, attd2, hw2, as2, ad2);
  gat2_final_kernel<<<gridW, BLK, 0, stream>>>(hw2, as2, ad2, bg2, offs, csr_src, out);
}

// Round 7
// 431.296 us; speedup vs baseline: 2.3904x; 1.2613x over previous
//
#include <hip/hip_runtime.h>
#include <cstdint>
#include <cstddef>

#define NN 30000
#define NE 480000

__device__ __forceinline__ float leakyf(float x){ return x > 0.f ? x : 0.2f * x; }
__device__ __forceinline__ float eluf(float x){ return x > 0.f ? x : expm1f(x); }

struct F4 { float x, y, z, w; };

__device__ __forceinline__ F4 ld4(const float* p){
  float4 v = *(const float4*)p;
  return F4{v.x, v.y, v.z, v.w};
}

// ---------------- CSR build ----------------

__global__ void zero_int_kernel(int* __restrict__ p, int n){
  int i = blockIdx.x * blockDim.x + threadIdx.x;
  if (i < n) p[i] = 0;
}

__global__ void count_kernel(const int* __restrict__ dst, int* __restrict__ deg, int E){
  int i = blockIdx.x * blockDim.x + threadIdx.x;
  if (i < E) atomicAdd(&deg[dst[i]], 1);
}

__global__ void scan1_kernel(const int* __restrict__ deg, int* __restrict__ offs,
                             int* __restrict__ bsum){
  __shared__ int sh[256];
  int blk = blockIdx.x, t = threadIdx.x, i = blk * 256 + t;
  int v = (i < NN) ? deg[i] : 0;
  sh[t] = v; __syncthreads();
  for (int o = 1; o < 256; o <<= 1){
    int tv = (t >= o) ? sh[t - o] : 0;
    __syncthreads();
    sh[t] += tv;
    __syncthreads();
  }
  if (i < NN) offs[i + 1] = sh[t];
  if (t == 255) bsum[blk] = sh[255];
}

__global__ void scan2_kernel(int* __restrict__ bsum, int nb){
  __shared__ int sh[256];
  int t = threadIdx.x;
  int v = (t < nb) ? bsum[t] : 0;
  sh[t] = v; __syncthreads();
  for (int o = 1; o < 256; o <<= 1){
    int tv = (t >= o) ? sh[t - o] : 0;
    __syncthreads();
    sh[t] += tv;
    __syncthreads();
  }
  if (t < nb) bsum[t] = sh[t];
}

__global__ void scan3_kernel(const int* __restrict__ bsum, int* __restrict__ offs){
  int i = blockIdx.x * 256 + threadIdx.x;
  if (i == 0) offs[0] = 0;
  if (i < NN){
    int blk = i >> 8;
    int add = blk ? bsum[blk - 1] : 0;
    offs[i + 1] += add;
  }
}

__global__ void scatter_kernel(const int* __restrict__ src, const int* __restrict__ dst,
                               const int* __restrict__ et, const int* __restrict__ offs,
                               int* __restrict__ cursor, int* __restrict__ csr_src,
                               int* __restrict__ csr_et, int E){
  int i = blockIdx.x * blockDim.x + threadIdx.x;
  if (i < E){
    int d = dst[i];
    int pos = offs[d] + atomicAdd(&cursor[d], 1);
    csr_src[pos] = src[i];
    csr_et[pos]  = et[i];
  }
}

// ---------------- weight concat: Wcat2[k][b*64+c] = basis2[b][k][c]; [k][256+c] = root2[k][c] ----

__global__ void wcat2_kernel(const float* __restrict__ basis2, const float* __restrict__ root2,
                             float* __restrict__ Wcat){
  int idx = blockIdx.x * 256 + threadIdx.x;
  if (idx >= 256 * 320) return;
  int k = idx / 320, col = idx - k * 320;
  float v;
  if (col < 256){
    int b = col >> 6, c = col & 63;
    v = basis2[((size_t)b * 256 + k) * 64 + c];
  } else {
    v = root2[(size_t)k * 64 + (col - 256)];
  }
  Wcat[idx] = v;
}

// ---------------- layer-1 basis-space aggregation (input space, 32-wide) ----------------

__global__ void agg1_kernel(const float* __restrict__ x, const float* __restrict__ comp,
                            const int* __restrict__ offs, const int* __restrict__ csr_src,
                            const int* __restrict__ csr_et, float* __restrict__ agg){
  int wid  = (blockIdx.x * blockDim.x + threadIdx.x) >> 6;
  int lane = threadIdx.x & 63;
  if (wid >= NN) return;
  int c = lane & 31, half = lane >> 5;
  int n0 = offs[wid], n1 = offs[wid + 1];
  float a0 = 0.f, a1 = 0.f, a2 = 0.f, a3 = 0.f;
  for (int k = n0 + half; k < n1; k += 2){
    int s = csr_src[k], e = csr_et[k];
    float v = x[(size_t)s * 32 + c];
    F4 cp = ld4(comp + (size_t)e * 4);
    a0 += cp.x * v; a1 += cp.y * v; a2 += cp.z * v; a3 += cp.w * v;
  }
  a0 += __shfl_xor(a0, 32);
  a1 += __shfl_xor(a1, 32);
  a2 += __shfl_xor(a2, 32);
  a3 += __shfl_xor(a3, 32);
  int dg = n1 - n0;
  float sc = 1.f / (float)(dg > 0 ? dg : 1);
  if (lane < 32){
    float* ar = agg + (size_t)wid * 128 + c;
    ar[0]  = a0 * sc;
    ar[32] = a1 * sc;
    ar[64] = a2 * sc;
    ar[96] = a3 * sc;
  }
}

// ---------------- 64x64-tile fused GEMM, 4x4 register microtile ----------------

template<bool ELU, bool ATT>
__global__ __launch_bounds__(256) void gemm64_kernel(
    const float* __restrict__ A1, int lda1, int K1,
    const float* __restrict__ W1, int ldw1,
    const float* __restrict__ A2, int lda2, int K2,
    const float* __restrict__ W2, int ldw2,
    const float* __restrict__ bias,
    const float* __restrict__ atts, const float* __restrict__ attd,
    float* __restrict__ Y, int ldy,
    float* __restrict__ as_, float* __restrict__ ad_,
    int nrows)
{
  __shared__ float At[64][68];
  __shared__ float Wl[64][68];
  int t = threadIdx.x;
  int tc = t & 15, tr = t >> 4;
  int cg = blockIdx.y;
  int nbase = blockIdx.x * 64;
  float acc[4][4];
  #pragma unroll
  for (int j = 0; j < 4; j++)
    #pragma unroll
    for (int i = 0; i < 4; i++) acc[j][i] = 0.f;

  for (int seg = 0; seg < 2; seg++){
    const float* A = seg ? A2 : A1;
    const float* W = seg ? W2 : W1;
    int lda = seg ? lda2 : lda1;
    int ldw = seg ? ldw2 : ldw1;
    int K   = seg ? K2 : K1;
    if (A == nullptr || K <= 0) continue;
    for (int k0 = 0; k0 < K; k0 += 64){
      #pragma unroll
      for (int i = 0; i < 4; i++){
        int e = i * 256 + t;
        int kk = e >> 4, c4 = (e & 15) << 2;
        float4 v = make_float4(0.f, 0.f, 0.f, 0.f);
        if (k0 + kk < K) v = *(const float4*)(W + (size_t)(k0 + kk) * ldw + cg * 64 + c4);
        *(float4*)&Wl[kk][c4] = v;
      }
      {
        int r = t >> 2;
        int n = nbase + r;
        #pragma unroll
        for (int i = 0; i < 4; i++){
          int c4 = ((t & 3) << 2) + (i << 4);
          float4 v = make_float4(0.f, 0.f, 0.f, 0.f);
          if (n < nrows && k0 + c4 < K) v = *(const float4*)(A + (size_t)n * lda + k0 + c4);
          At[c4 + 0][r] = v.x;
          At[c4 + 1][r] = v.y;
          At[c4 + 2][r] = v.z;
          At[c4 + 3][r] = v.w;
        }
      }
      __syncthreads();
      #pragma unroll 8
      for (int k = 0; k < 64; k++){
        float4 av = *(const float4*)&At[k][tr * 4];
        float4 wv = *(const float4*)&Wl[k][tc * 4];
        const float* pa = (const float*)&av;
        const float* pw = (const float*)&wv;
        #pragma unroll
        for (int j = 0; j < 4; j++)
          #pragma unroll
          for (int i = 0; i < 4; i++)
            acc[j][i] = fmaf(pa[j], pw[i], acc[j][i]);
      }
      __syncthreads();
    }
  }

  float b0 = 0.f, b1 = 0.f, b2 = 0.f, b3 = 0.f;
  if (bias){
    b0 = bias[cg * 64 + tc * 4 + 0];
    b1 = bias[cg * 64 + tc * 4 + 1];
    b2 = bias[cg * 64 + tc * 4 + 2];
    b3 = bias[cg * 64 + tc * 4 + 3];
  }
  #pragma unroll
  for (int j = 0; j < 4; j++){
    int n = nbase + tr * 4 + j;
    if (n < nrows){
      float y0 = acc[j][0] + b0, y1 = acc[j][1] + b1, y2 = acc[j][2] + b2, y3 = acc[j][3] + b3;
      if (ELU){ y0 = eluf(y0); y1 = eluf(y1); y2 = eluf(y2); y3 = eluf(y3); }
      *(float4*)(Y + (size_t)n * ldy + cg * 64 + tc * 4) = make_float4(y0, y1, y2, y3);
    }
  }
  if (ATT){
    float ta0 = atts[cg * 64 + tc * 4 + 0], ta1 = atts[cg * 64 + tc * 4 + 1];
    float ta2 = atts[cg * 64 + tc * 4 + 2], ta3 = atts[cg * 64 + tc * 4 + 3];
    float tb0 = attd[cg * 64 + tc * 4 + 0], tb1 = attd[cg * 64 + tc * 4 + 1];
    float tb2 = attd[cg * 64 + tc * 4 + 2], tb3 = attd[cg * 64 + tc * 4 + 3];
    #pragma unroll
    for (int j = 0; j < 4; j++){
      float ps = acc[j][0]*ta0 + acc[j][1]*ta1 + acc[j][2]*ta2 + acc[j][3]*ta3;
      float pd = acc[j][0]*tb0 + acc[j][1]*tb1 + acc[j][2]*tb2 + acc[j][3]*tb3;
      #pragma unroll
      for (int o = 8; o; o >>= 1){ ps += __shfl_xor(ps, o); pd += __shfl_xor(pd, o); }
      int n = nbase + tr * 4 + j;
      if (tc == 0 && n < nrows){ as_[n * 4 + cg] = ps; ad_[n * 4 + cg] = pd; }
    }
  }
}

// ---------------- layer-3 aggregate (transform-first) ----------------
// h3[n,o] = elu( (1/deg) * sum_e comp[et, b]*xb2[src, b*64+o]  + xb2[n, 256+o] + bias[o] )
// wave per node; lane l reads xb2[src*320 + l*4] (float4), b = l>>4; 2-shfl segment reduce.

__global__ void rgcn2_agg_kernel(const float* __restrict__ xb, const float* __restrict__ comp,
                                 const float* __restrict__ bias, const int* __restrict__ offs,
                                 const int* __restrict__ csr_src, const int* __restrict__ csr_et,
                                 float* __restrict__ h3){
  int wid  = (blockIdx.x * blockDim.x + threadIdx.x) >> 6;
  int lane = threadIdx.x & 63;
  if (wid >= NN) return;
  int b = lane >> 4, q = lane & 15;
  int n0 = offs[wid], n1 = offs[wid + 1];
  float ax = 0.f, ay = 0.f, az = 0.f, aw = 0.f;
  int k = n0;
  for (; k + 1 < n1; k += 2){
    int s0 = csr_src[k],     e0 = csr_et[k];
    int s1 = csr_src[k + 1], e1 = csr_et[k + 1];
    float c0 = comp[e0 * 4 + b];
    float c1 = comp[e1 * 4 + b];
    float4 v0 = *(const float4*)(xb + (size_t)s0 * 320 + lane * 4);
    float4 v1 = *(const float4*)(xb + (size_t)s1 * 320 + lane * 4);
    ax += c0 * v0.x + c1 * v1.x;
    ay += c0 * v0.y + c1 * v1.y;
    az += c0 * v0.z + c1 * v1.z;
    aw += c0 * v0.w + c1 * v1.w;
  }
  if (k < n1){
    int s = csr_src[k], e = csr_et[k];
    float c0 = comp[e * 4 + b];
    float4 v = *(const float4*)(xb + (size_t)s * 320 + lane * 4);
    ax += c0 * v.x; ay += c0 * v.y; az += c0 * v.z; aw += c0 * v.w;
  }
  // reduce across the 4 basis segments (lanes l, l^16, l^32, l^48)
  ax += __shfl_xor(ax, 16); ax += __shfl_xor(ax, 32);
  ay += __shfl_xor(ay, 16); ay += __shfl_xor(ay, 32);
  az += __shfl_xor(az, 16); az += __shfl_xor(az, 32);
  aw += __shfl_xor(aw, 16); aw += __shfl_xor(aw, 32);
  int dg = n1 - n0;
  float sc = 1.f / (float)(dg > 0 ? dg : 1);
  if (lane < 16){
    float4 r  = *(const float4*)(xb + (size_t)wid * 320 + 256 + q * 4);
    float4 bb = *(const float4*)(bias + q * 4);
    float4 o4;
    o4.x = eluf(ax * sc + r.x + bb.x);
    o4.y = eluf(ay * sc + r.y + bb.y);
    o4.z = eluf(az * sc + r.z + bb.z);
    o4.w = eluf(aw * sc + r.w + bb.w);
    *(float4*)(h3 + (size_t)wid * 64 + q * 4) = o4;
  }
}

// ---------------- GAT ----------------

__global__ void gat1_agg_kernel(const float* __restrict__ hw, const float* __restrict__ as_,
                                const float* __restrict__ ad_, const float* __restrict__ bias,
                                const int* __restrict__ offs, const int* __restrict__ csr_src,
                                float* __restrict__ out){
  int wid  = (blockIdx.x * blockDim.x + threadIdx.x) >> 6;
  int lane = threadIdx.x & 63;
  if (wid >= NN) return;
  int n0 = offs[wid], n1 = offs[wid + 1];
  int h    = lane & 3;
  int hseg = lane >> 4;
  float adn = ad_[wid * 4 + h];
  float es  = leakyf(as_[wid * 4 + h] + adn);
  float m = es;
  for (int k = n0 + (lane >> 2); k < n1; k += 16){
    int s = csr_src[k];
    m = fmaxf(m, leakyf(as_[s * 4 + h] + adn));
  }
  #pragma unroll
  for (int o = 4; o < 64; o <<= 1) m = fmaxf(m, __shfl_xor(m, o));
  float den = 0.f;
  float4 acc = make_float4(0.f, 0.f, 0.f, 0.f);
  for (int base = n0; base < n1; base += 16){
    int k = base + (lane >> 2);
    int s = 0; float p = 0.f;
    if (k < n1){
      s = csr_src[k];
      p = expf(leakyf(as_[s * 4 + h] + adn) - m);
    }
    den += p;
    int cnt = min(16, n1 - base);
    for (int jj = 0; jj < cnt; jj++){
      float pj = __shfl(p, (jj << 2) | hseg);
      int  sj  = __shfl(s, (jj << 2));
      float4 v = *(const float4*)(hw + (size_t)sj * 256 + lane * 4);
      acc.x += pj * v.x; acc.y += pj * v.y; acc.z += pj * v.z; acc.w += pj * v.w;
    }
  }
  #pragma unroll
  for (int o = 4; o < 64; o <<= 1) den += __shfl_xor(den, o);
  float ps   = expf(es - m);
  float psh  = __shfl(ps, hseg);
  float denh = __shfl(den, hseg) + psh;
  float4 v = *(const float4*)(hw + (size_t)wid * 256 + lane * 4);
  acc.x += psh * v.x; acc.y += psh * v.y; acc.z += psh * v.z; acc.w += psh * v.w;
  float4 bb = *(const float4*)(bias + lane * 4);
  float4 o4;
  o4.x = eluf(acc.x / denh + bb.x);
  o4.y = eluf(acc.y / denh + bb.y);
  o4.z = eluf(acc.z / denh + bb.z);
  o4.w = eluf(acc.w / denh + bb.w);
  *(float4*)(out + (size_t)wid * 256 + lane * 4) = o4;
}

__global__ void gat_lin2_kernel(const float* __restrict__ h, const float* __restrict__ W,
                                const float* __restrict__ atts, const float* __restrict__ attd,
                                float* __restrict__ hw, float* __restrict__ as_, float* __restrict__ ad_){
  int wid  = (blockIdx.x * blockDim.x + threadIdx.x) >> 6;
  int lane = threadIdx.x & 63;
  if (wid >= NN) return;
  float acc = 0.f;
  if (lane < 12){
    const float* hr = h + (size_t)wid * 64;
    const float* Wc = W + lane;
    #pragma unroll 8
    for (int i = 0; i < 64; i++) acc += hr[i] * Wc[(size_t)i * 12];
    hw[(size_t)wid * 12 + lane] = acc;
  }
  float ts = (lane < 12) ? acc * atts[lane] : 0.f;
  float td = (lane < 12) ? acc * attd[lane] : 0.f;
  int b = (lane < 4) ? lane * 3 : 0;
  float s0 = __shfl(ts, b) + __shfl(ts, b + 1) + __shfl(ts, b + 2);
  float d0 = __shfl(td, b) + __shfl(td, b + 1) + __shfl(td, b + 2);
  if (lane < 4){ as_[wid * 4 + lane] = s0; ad_[wid * 4 + lane] = d0; }
}

__global__ void gat2_final_kernel(const float* __restrict__ hw, const float* __restrict__ as_,
                                  const float* __restrict__ ad_, const float* __restrict__ bg2,
                                  const int* __restrict__ offs, const int* __restrict__ csr_src,
                                  float* __restrict__ out){
  int wid  = (blockIdx.x * blockDim.x + threadIdx.x) >> 6;
  int lane = threadIdx.x & 63;
  if (wid >= NN) return;
  int n0 = offs[wid], n1 = offs[wid + 1];
  F4 adn = ld4(ad_ + (size_t)wid * 4);
  F4 asn = ld4(as_ + (size_t)wid * 4);
  F4 es{leakyf(asn.x + adn.x), leakyf(asn.y + adn.y), leakyf(asn.z + adn.z), leakyf(asn.w + adn.w)};
  F4 m = es;
  for (int k = n0 + lane; k < n1; k += 64){
    int s = csr_src[k];
    F4 a = ld4(as_ + (size_t)s * 4);
    m.x = fmaxf(m.x, leakyf(a.x + adn.x));
    m.y = fmaxf(m.y, leakyf(a.y + adn.y));
    m.z = fmaxf(m.z, leakyf(a.z + adn.z));
    m.w = fmaxf(m.w, leakyf(a.w + adn.w));
  }
  #pragma unroll
  for (int o = 32; o; o >>= 1){
    m.x = fmaxf(m.x, __shfl_xor(m.x, o));
    m.y = fmaxf(m.y, __shfl_xor(m.y, o));
    m.z = fmaxf(m.z, __shfl_xor(m.z, o));
    m.w = fmaxf(m.w, __shfl_xor(m.w, o));
  }
  F4 ps{expf(es.x - m.x), expf(es.y - m.y), expf(es.z - m.z), expf(es.w - m.w)};
  float acc[12];
  #pragma unroll
  for (int j = 0; j < 12; j++) acc[j] = 0.f;
  F4 denp{0.f, 0.f, 0.f, 0.f};
  for (int k = n0 + lane; k < n1; k += 64){
    int s = csr_src[k];
    F4 a = ld4(as_ + (size_t)s * 4);
    F4 p{expf(leakyf(a.x + adn.x) - m.x), expf(leakyf(a.y + adn.y) - m.y),
         expf(leakyf(a.z + adn.z) - m.z), expf(leakyf(a.w + adn.w) - m.w)};
    denp.x += p.x; denp.y += p.y; denp.z += p.z; denp.w += p.w;
    const float* hb = hw + (size_t)s * 12;
    F4 h0 = ld4(hb), h1 = ld4(hb + 4), h2 = ld4(hb + 8);
    acc[0] += p.x * h0.x; acc[1]  += p.x * h0.y; acc[2]  += p.x * h0.z;
    acc[3] += p.y * h0.w; acc[4]  += p.y * h1.x; acc[5]  += p.y * h1.y;
    acc[6] += p.z * h1.z; acc[7]  += p.z * h1.w; acc[8]  += p.z * h2.x;
    acc[9] += p.w * h2.y; acc[10] += p.w * h2.z; acc[11] += p.w * h2.w;
  }
  #pragma unroll
  for (int o = 32; o; o >>= 1){
    denp.x += __shfl_xor(denp.x, o);
    denp.y += __shfl_xor(denp.y, o);
    denp.z += __shfl_xor(denp.z, o);
    denp.w += __shfl_xor(denp.w, o);
    #pragma unroll
    for (int j = 0; j < 12; j++) acc[j] += __shfl_xor(acc[j], o);
  }
  if (lane == 0){
    const float* hn = hw + (size_t)wid * 12;
    float dn[4]  = {denp.x + ps.x, denp.y + ps.y, denp.z + ps.z, denp.w + ps.w};
    float psv[4] = {ps.x, ps.y, ps.z, ps.w};
    float tot = 0.f;
    #pragma unroll
    for (int h_ = 0; h_ < 4; h_++){
      #pragma unroll
      for (int c = 0; c < 3; c++){
        float num = acc[h_ * 3 + c] + psv[h_] * hn[h_ * 3 + c];
        tot += num / dn[h_];
      }
    }
    tot = tot / 12.f + (bg2[0] + bg2[1] + bg2[2]) / 3.f;
    out[wid] = tanhf(tot);
  }
}

// ---------------- launch ----------------

extern "C" void kernel_launch(void* const* d_in, const int* in_sizes, int n_in,
                              void* d_out, int out_size, void* d_ws, size_t ws_size,
                              hipStream_t stream){
  const float* x      = (const float*)d_in[0];
  const int*   ei     = (const int*)d_in[1];
  const int*   et     = (const int*)d_in[2];
  const float* basis1 = (const float*)d_in[3];
  const float* comp1  = (const float*)d_in[4];
  const float* root1  = (const float*)d_in[5];
  const float* brg1   = (const float*)d_in[6];
  const float* Wg1    = (const float*)d_in[7];
  const float* atts1  = (const float*)d_in[8];
  const float* attd1  = (const float*)d_in[9];
  const float* bg1    = (const float*)d_in[10];
  const float* basis2 = (const float*)d_in[11];
  const float* comp2  = (const float*)d_in[12];
  const float* root2  = (const float*)d_in[13];
  const float* brg2   = (const float*)d_in[14];
  const float* Wg2    = (const float*)d_in[15];
  const float* atts2  = (const float*)d_in[16];
  const float* attd2  = (const float*)d_in[17];
  const float* bg2    = (const float*)d_in[18];
  float* out = (float*)d_out;

  const int* src = ei;
  const int* dst = ei + NE;

  char* ws = (char*)d_ws;
  size_t off = 0;
  auto alloc = [&](size_t bytes) -> void* {
    void* p = ws + off;
    off = (off + bytes + 255) & ~(size_t)255;
    return p;
  };
  // persistent
  int*   deg     = (int*)alloc((size_t)NN * 4);
  int*   cursor  = (int*)alloc((size_t)NN * 4);
  int*   offs    = (int*)alloc((size_t)(NN + 1) * 4);
  int*   bsum    = (int*)alloc((size_t)256 * 4);
  int*   csr_src = (int*)alloc((size_t)NE * 4);
  int*   csr_et  = (int*)alloc((size_t)NE * 4);
  float* Wcat2   = (float*)alloc((size_t)256 * 320 * 4);
  float* h1      = (float*)alloc((size_t)NN * 64 * 4);
  float* h2      = (float*)alloc((size_t)NN * 256 * 4);
  float* h3      = (float*)alloc((size_t)NN * 64 * 4);
  float* hw2     = (float*)alloc((size_t)NN * 12 * 4);
  float* as1     = (float*)alloc((size_t)NN * 4 * 4);
  float* ad1     = (float*)alloc((size_t)NN * 4 * 4);
  float* as2     = (float*)alloc((size_t)NN * 4 * 4);
  float* ad2     = (float*)alloc((size_t)NN * 4 * 4);
  // scratch union: agg1[NN*128] -> hW1[NN*256] -> xb2[NN*320]
  float* S       = (float*)alloc((size_t)NN * 320 * 4);
  float* agg1    = S;
  float* hW1     = S;
  float* xb2     = S;
  (void)ws_size; (void)n_in; (void)in_sizes; (void)out_size;

  const int BLK = 256;
  int gridN  = (NN + BLK - 1) / BLK;
  int gridE  = (NE + BLK - 1) / BLK;
  int gridW  = (NN + 3) / 4;
  int gridM  = (NN + 63) / 64;          // 64-row GEMM tiles (469)

  // CSR build + weight concat
  zero_int_kernel<<<gridN, BLK, 0, stream>>>(deg, NN);
  zero_int_kernel<<<gridN, BLK, 0, stream>>>(cursor, NN);
  count_kernel<<<gridE, BLK, 0, stream>>>(dst, deg, NE);
  wcat2_kernel<<<(256 * 320 + 255) / 256, BLK, 0, stream>>>(basis2, root2, Wcat2);
  scan1_kernel<<<gridN, BLK, 0, stream>>>(deg, offs, bsum);
  scan2_kernel<<<1, BLK, 0, stream>>>(bsum, gridN);
  scan3_kernel<<<gridN, BLK, 0, stream>>>(bsum, offs);
  scatter_kernel<<<gridE, BLK, 0, stream>>>(src, dst, et, offs, cursor, csr_src, csr_et, NE);

  // Layer 1: RGCN (32 -> 64) + elu: agg-first, fused GEMM (basis + root + bias + elu)
  agg1_kernel<<<gridW, BLK, 0, stream>>>(x, comp1, offs, csr_src, csr_et, agg1);
  gemm64_kernel<true, false><<<dim3(gridM, 1), BLK, 0, stream>>>(
      agg1, 128, 128, basis1, 64,
      x, 32, 32, root1, 64,
      brg1, nullptr, nullptr, h1, 64, nullptr, nullptr, NN);

  // Layer 2: GAT (64 -> 256 concat): linear + fused attention logits, then softmax-agg
  gemm64_kernel<false, true><<<dim3(gridM, 4), BLK, 0, stream>>>(
      h1, 64, 64, Wg1, 256,
      nullptr, 0, 0, nullptr, 0,
      nullptr, atts1, attd1, hW1, 256, as1, ad1, NN);
  gat1_agg_kernel<<<gridW, BLK, 0, stream>>>(hW1, as1, ad1, bg1, offs, csr_src, h2);

  // Layer 3: RGCN (256 -> 64) + elu: transform-first
  // xb2[n, 0..255] = h2 @ basis2 (4 bases concat); xb2[n, 256..319] = h2 @ root2
  gemm64_kernel<false, false><<<dim3(gridM, 5), BLK, 0, stream>>>(
      h2, 256, 256, Wcat2, 320,
      nullptr, 0, 0, nullptr, 0,
      nullptr, nullptr, nullptr, xb2, 320, nullptr, nullptr, NN);
  rgcn2_agg_kernel<<<gridW, BLK, 0, stream>>>(xb2, comp2, brg2, offs, csr_src, csr_et, h3);

  // Layer 4: GAT (64 -> 4x3, mean heads) + mean classes + tanh
  gat_lin2_kernel<<<gridW, BLK, 0, stream>>>(h3, Wg2, atts2, attd2, hw2, as2, ad2);
  gat2_final_kernel<<<gridW, BLK, 0, stream>>>(hw2, as2, ad2, bg2, offs, csr_src, out);
}